// Round 4
// baseline (868.865 us; speedup 1.0000x reference)
//
#include <hip/hip_runtime.h>
#include <math.h>

static constexpr int S = 2048;          // tokens (B=1)
static constexpr int D = 1024;          // model dim
static constexpr int H = 16;            // heads
static constexpr int HD = 64;           // head dim
static constexpr int E = 8;             // experts
static constexpr int F = 2048;          // ffn dim
static constexpr int NSLOTS = S * 2;    // 4096
static constexpr int NPAD = NSLOTS + 128;

typedef __attribute__((ext_vector_type(8))) short bf16x8;
typedef __attribute__((ext_vector_type(4))) float f32x4;

__device__ __forceinline__ float bf2f(ushort u) {
    uint32_t x = ((uint32_t)u) << 16; float f; __builtin_memcpy(&f, &x, 4); return f;
}
__device__ __forceinline__ ushort f2bf(float f) {
    uint32_t x; __builtin_memcpy(&x, &f, 4);
    return (ushort)((x + 0x7fffu + ((x >> 16) & 1u)) >> 16);
}
__device__ __forceinline__ void async_copy16(const void* gptr, void* ldsptr) {
    __builtin_amdgcn_global_load_lds(
        (const __attribute__((address_space(1))) void*)gptr,
        (__attribute__((address_space(3))) void*)ldsptr, 16, 0, 0);
}

// ============ cast + transpose fp32 [K][N] -> bf16 [N][K] (single plane, MoE weights) ============
__global__ __launch_bounds__(256) void castT_kernel(const float* __restrict__ src,
    ushort* __restrict__ dst, int K, int N)
{
    __shared__ float T[64][65];
    int z = blockIdx.z;
    src += (size_t)z * K * N; dst += (size_t)z * K * N;
    int k0 = blockIdx.y * 64, n0 = blockIdx.x * 64;
    int t = threadIdx.x;
    int r = t >> 4, c4 = (t & 15) * 4;
#pragma unroll
    for (int it = 0; it < 4; it++) {
        float4 v = *(const float4*)(src + (size_t)(k0 + r + it * 16) * N + n0 + c4);
        T[r + it * 16][c4 + 0] = v.x; T[r + it * 16][c4 + 1] = v.y;
        T[r + it * 16][c4 + 2] = v.z; T[r + it * 16][c4 + 3] = v.w;
    }
    __syncthreads();
#pragma unroll
    for (int it = 0; it < 4; it++) {
        int rr = r + it * 16;
        ushort4 o;
        o.x = f2bf(T[c4 + 0][rr]); o.y = f2bf(T[c4 + 1][rr]);
        o.z = f2bf(T[c4 + 2][rr]); o.w = f2bf(T[c4 + 3][rr]);
        *(ushort4*)(dst + (size_t)(n0 + rr) * K + k0 + c4) = o;
    }
}

// ============ cast + transpose fp32 [K][N] -> bf16x2 hi/lo planes [N][K] ============
__global__ __launch_bounds__(256) void castT2_kernel(const float* __restrict__ src,
    ushort* __restrict__ dh, ushort* __restrict__ dl, int K, int N)
{
    __shared__ float T[64][65];
    src += (size_t)blockIdx.z * K * N;
    dh += (size_t)blockIdx.z * K * N; dl += (size_t)blockIdx.z * K * N;
    int k0 = blockIdx.y * 64, n0 = blockIdx.x * 64;
    int t = threadIdx.x;
    int r = t >> 4, c4 = (t & 15) * 4;
#pragma unroll
    for (int it = 0; it < 4; it++) {
        float4 v = *(const float4*)(src + (size_t)(k0 + r + it * 16) * N + n0 + c4);
        T[r + it * 16][c4 + 0] = v.x; T[r + it * 16][c4 + 1] = v.y;
        T[r + it * 16][c4 + 2] = v.z; T[r + it * 16][c4 + 3] = v.w;
    }
    __syncthreads();
#pragma unroll
    for (int it = 0; it < 4; it++) {
        int rr = r + it * 16;
        ushort4 oh, ol;
        float v0 = T[c4 + 0][rr], v1 = T[c4 + 1][rr], v2 = T[c4 + 2][rr], v3 = T[c4 + 3][rr];
        oh.x = f2bf(v0); ol.x = f2bf(v0 - bf2f(oh.x));
        oh.y = f2bf(v1); ol.y = f2bf(v1 - bf2f(oh.y));
        oh.z = f2bf(v2); ol.z = f2bf(v2 - bf2f(oh.z));
        oh.w = f2bf(v3); ol.w = f2bf(v3 - bf2f(oh.w));
        *(ushort4*)(dh + (size_t)(n0 + rr) * K + k0 + c4) = oh;
        *(ushort4*)(dl + (size_t)(n0 + rr) * K + k0 + c4) = ol;
    }
}

// ============ LayerNorm: optional fp32 / bf16-hi / bf16-lo outputs ============
__global__ __launch_bounds__(256) void ln_kernel(const float* __restrict__ x,
    const float* __restrict__ w, const float* __restrict__ b,
    float* __restrict__ yf, ushort* __restrict__ yh, ushort* __restrict__ yl)
{
    int t = blockIdx.x, tid = threadIdx.x;
    __shared__ float redx[256];
    __shared__ float redy[256];
    const float* xr = x + (size_t)t * D;
    float4 xv = *(const float4*)(xr + tid * 4);
    redx[tid] = xv.x + xv.y + xv.z + xv.w;
    redy[tid] = xv.x * xv.x + xv.y * xv.y + xv.z * xv.z + xv.w * xv.w;
    __syncthreads();
    for (int st = 128; st > 0; st >>= 1) {
        if (tid < st) { redx[tid] += redx[tid + st]; redy[tid] += redy[tid + st]; }
        __syncthreads();
    }
    float mean = redx[0] * (1.0f / D);
    float var  = redy[0] * (1.0f / D) - mean * mean;
    float rstd = rsqrtf(var + 1e-5f);
    float4 wv = *(const float4*)(w + tid * 4);
    float4 bv = *(const float4*)(b + tid * 4);
    float4 o;
    o.x = (xv.x - mean) * rstd * wv.x + bv.x;
    o.y = (xv.y - mean) * rstd * wv.y + bv.y;
    o.z = (xv.z - mean) * rstd * wv.z + bv.z;
    o.w = (xv.w - mean) * rstd * wv.w + bv.w;
    if (yf) *(float4*)(yf + (size_t)t * D + tid * 4) = o;
    ushort4 oh;
    oh.x = f2bf(o.x); oh.y = f2bf(o.y); oh.z = f2bf(o.z); oh.w = f2bf(o.w);
    if (yh) *(ushort4*)(yh + (size_t)t * D + tid * 4) = oh;
    if (yl) {
        ushort4 ol;
        ol.x = f2bf(o.x - bf2f(oh.x)); ol.y = f2bf(o.y - bf2f(oh.y));
        ol.z = f2bf(o.z - bf2f(oh.z)); ol.w = f2bf(o.w - bf2f(oh.w));
        *(ushort4*)(yl + (size_t)t * D + tid * 4) = ol;
    }
}

// ============ RoPE + bf16 hi/lo cast. Q pre-scaled by 0.125*log2(e) for exp2-softmax ============
__global__ __launch_bounds__(512) void rope_cast(const float* __restrict__ q,
    const float* __restrict__ k, ushort* __restrict__ qh, ushort* __restrict__ ql,
    ushort* __restrict__ kh, ushort* __restrict__ kl)
{
    int t = blockIdx.x;
    int idx = threadIdx.x;
    int hh = idx >> 5, i = idx & 31;
    float invf = powf(10000.0f, -(float)i / 32.0f);
    float ang = (float)t * invf;
    float cc = cosf(ang), ss = sinf(ang);
    size_t base = (size_t)t * D + hh * HD + i;
    const float QS = 0.125f * 1.4426950408889634f;
    float q1 = q[base], q2 = q[base + 32];
    float qr1 = (q1 * cc - q2 * ss) * QS;
    float qr2 = (q2 * cc + q1 * ss) * QS;
    ushort h1 = f2bf(qr1); qh[base] = h1;      ql[base] = f2bf(qr1 - bf2f(h1));
    ushort h2 = f2bf(qr2); qh[base + 32] = h2; ql[base + 32] = f2bf(qr2 - bf2f(h2));
    float k1 = k[base], k2 = k[base + 32];
    float kr1 = k1 * cc - k2 * ss;
    float kr2 = k2 * cc + k1 * ss;
    ushort h3 = f2bf(kr1); kh[base] = h3;      kl[base] = f2bf(kr1 - bf2f(h3));
    ushort h4 = f2bf(kr2); kh[base + 32] = h4; kl[base + 32] = f2bf(kr2 - bf2f(h4));
}

// ============ bf16x2 (fp32-emulated) MFMA k-loop: 128x128 tile, BK=32 ============
// Depth-1 pipelined: per iter {vmcnt(0); barrier; issue STAGE(t+1); ds_read+MFMA(t)}.
__device__ __forceinline__ void stage_m2(const ushort* __restrict__ Ah_g,
    const ushort* __restrict__ Al_g, const ushort* __restrict__ Bh_g,
    const ushort* __restrict__ Bl_g, int lda, int ldb, int kbase,
    ushort* sAh, ushort* sAl, ushort* sBh, ushort* sBl, int tid, int w)
{
#pragma unroll
    for (int it = 0; it < 2; it++) {
        int c = it * 256 + tid;
        int ckc = c >> 7, r = c & 127;
        int loff = (it * 256 + w * 64) * 8;
        size_t ga = (size_t)r * lda + kbase + ckc * 8;
        size_t gb = (size_t)r * ldb + kbase + ckc * 8;
        async_copy16(Ah_g + ga, sAh + loff);
        async_copy16(Al_g + ga, sAl + loff);
        async_copy16(Bh_g + gb, sBh + loff);
        async_copy16(Bl_g + gb, sBl + loff);
    }
}

__device__ __forceinline__ void mfma2_kloop(const ushort* __restrict__ Ah_g,
    const ushort* __restrict__ Al_g, const ushort* __restrict__ Bh_g,
    const ushort* __restrict__ Bl_g, int lda, int ldb, int K,
    ushort (&sAh)[2][4096], ushort (&sAl)[2][4096],
    ushort (&sBh)[2][4096], ushort (&sBl)[2][4096], f32x4 (&acc)[4][4])
{
    const int tid = threadIdx.x;
    const int w = tid >> 6, l = tid & 63;
    const int wm = (w >> 1) * 64, wn = (w & 1) * 64;
    const int kc = l >> 4, lr = l & 15;
    const int NT = K / 32;
    stage_m2(Ah_g, Al_g, Bh_g, Bl_g, lda, ldb, 0, sAh[0], sAl[0], sBh[0], sBl[0], tid, w);
    for (int t = 0; t < NT; ++t) {
        const int cur = t & 1;
        asm volatile("s_waitcnt vmcnt(0)" ::: "memory");
        __builtin_amdgcn_s_barrier();
        __builtin_amdgcn_sched_barrier(0);
        if (t + 1 < NT)
            stage_m2(Ah_g, Al_g, Bh_g, Bl_g, lda, ldb, (t + 1) * 32,
                     sAh[1 - cur], sAl[1 - cur], sBh[1 - cur], sBl[1 - cur], tid, w);
        bf16x8 ah[4], al[4], bh[4], bl[4];
#pragma unroll
        for (int f = 0; f < 4; f++) {
            int ao = (kc * 128 + wm + f * 16 + lr) * 8;
            int bo = (kc * 128 + wn + f * 16 + lr) * 8;
            ah[f] = *(const bf16x8*)(sAh[cur] + ao);
            al[f] = *(const bf16x8*)(sAl[cur] + ao);
            bh[f] = *(const bf16x8*)(sBh[cur] + bo);
            bl[f] = *(const bf16x8*)(sBl[cur] + bo);
        }
#pragma unroll
        for (int fm = 0; fm < 4; fm++)
#pragma unroll
            for (int fn = 0; fn < 4; fn++) {
                acc[fm][fn] = __builtin_amdgcn_mfma_f32_16x16x32_bf16(ah[fm], bh[fn], acc[fm][fn], 0, 0, 0);
                acc[fm][fn] = __builtin_amdgcn_mfma_f32_16x16x32_bf16(ah[fm], bl[fn], acc[fm][fn], 0, 0, 0);
                acc[fm][fn] = __builtin_amdgcn_mfma_f32_16x16x32_bf16(al[fm], bh[fn], acc[fm][fn], 0, 0, 0);
            }
    }
}

// ============ QKV GEMM bf16x2 -> fp32 out (z selects q/k/v) ============
__global__ __launch_bounds__(256) void qkv_mfma2(const ushort* __restrict__ xh,
    const ushort* __restrict__ xl,
    const ushort* __restrict__ wqh, const ushort* __restrict__ wql,
    const ushort* __restrict__ wkh, const ushort* __restrict__ wkl,
    const ushort* __restrict__ wvh, const ushort* __restrict__ wvl,
    float* __restrict__ qo, float* __restrict__ ko, float* __restrict__ vo)
{
    __shared__ ushort sAh[2][4096], sAl[2][4096], sBh[2][4096], sBl[2][4096];
    const ushort* Bh = blockIdx.z == 0 ? wqh : (blockIdx.z == 1 ? wkh : wvh);
    const ushort* Bl = blockIdx.z == 0 ? wql : (blockIdx.z == 1 ? wkl : wvl);
    float* C = blockIdx.z == 0 ? qo : (blockIdx.z == 1 ? ko : vo);
    int m0 = blockIdx.y * 128, n0 = blockIdx.x * 128;
    f32x4 acc[4][4];
#pragma unroll
    for (int i = 0; i < 4; i++)
#pragma unroll
        for (int j = 0; j < 4; j++) acc[i][j] = (f32x4){0.f, 0.f, 0.f, 0.f};
    mfma2_kloop(xh + (size_t)m0 * D, xl + (size_t)m0 * D,
                Bh + (size_t)n0 * D, Bl + (size_t)n0 * D, D, D, D,
                sAh, sAl, sBh, sBl, acc);
    const int l = threadIdx.x & 63, w = threadIdx.x >> 6;
    const int wm = (w >> 1) * 64, wn = (w & 1) * 64;
#pragma unroll
    for (int fm = 0; fm < 4; fm++)
#pragma unroll
        for (int fn = 0; fn < 4; fn++)
#pragma unroll
            for (int r = 0; r < 4; r++) {
                int row = m0 + wm + fm * 16 + (l >> 4) * 4 + r;
                int col = n0 + wn + fn * 16 + (l & 15);
                C[(size_t)row * D + col] = acc[fm][fn][r];
            }
}

// ============ WO GEMM bf16x2 + residual -> fp32 ============
__global__ __launch_bounds__(256) void wo_mfma2(const ushort* __restrict__ ah,
    const ushort* __restrict__ al, const ushort* __restrict__ wh, const ushort* __restrict__ wl,
    const float* __restrict__ resid, float* __restrict__ Cout)
{
    __shared__ ushort sAh[2][4096], sAl[2][4096], sBh[2][4096], sBl[2][4096];
    int m0 = blockIdx.y * 128, n0 = blockIdx.x * 128;
    f32x4 acc[4][4];
#pragma unroll
    for (int i = 0; i < 4; i++)
#pragma unroll
        for (int j = 0; j < 4; j++) acc[i][j] = (f32x4){0.f, 0.f, 0.f, 0.f};
    mfma2_kloop(ah + (size_t)m0 * D, al + (size_t)m0 * D,
                wh + (size_t)n0 * D, wl + (size_t)n0 * D, D, D, D,
                sAh, sAl, sBh, sBl, acc);
    const int l = threadIdx.x & 63, w = threadIdx.x >> 6;
    const int wm = (w >> 1) * 64, wn = (w & 1) * 64;
#pragma unroll
    for (int fm = 0; fm < 4; fm++)
#pragma unroll
        for (int fn = 0; fn < 4; fn++)
#pragma unroll
            for (int r = 0; r < 4; r++) {
                int row = m0 + wm + fm * 16 + (l >> 4) * 4 + r;
                int col = n0 + wn + fn * 16 + (l & 15);
                Cout[(size_t)row * D + col] = acc[fm][fn][r] + resid[(size_t)row * D + col];
            }
}

// ============ Flash attention via MFMA (bf16x2 triple-product QK^T and PV) ============
// Grid: (32, 16) = 512 blocks, one 64-row q-tile each -> 2 blocks/CU (80 KB LDS).
// XCD-aware bijective swizzle: wgid = (n&7)*64 + n>>3 gives each XCD 2 heads
// (K/V 2 MB fits 4 MB L2); within an XCD launch order walks qt 31->0 (LPT).
__global__ __launch_bounds__(256) void attn_mfma(
    const ushort* __restrict__ qhp, const ushort* __restrict__ qlp,
    const ushort* __restrict__ khp, const ushort* __restrict__ klp,
    const ushort* __restrict__ vth, const ushort* __restrict__ vtl,
    ushort* __restrict__ oh_out, ushort* __restrict__ ol_out)
{
    __shared__ ushort sK[2][2][4096];   // [buf][hi/lo][kc*64+ktok][8]  32 KB
    __shared__ ushort sV[2][2][4096];   // [buf][hi/lo][kc*64+hd][8]    32 KB
    __shared__ ushort sP[4][2][1024];   // [wave][hi/lo][chunk*16+row][8] 16 KB
    const int n = blockIdx.y * 32 + blockIdx.x;
    const int wg = ((n & 7) << 6) + (n >> 3);   // bijective 512-block XCD swizzle
    const int h = wg >> 5;
    const int qt = 31 - (wg & 31);              // big q-tiles dispatch first (LPT)
    const int tid = threadIdx.x;
    const int w = tid >> 6, l = tid & 63;
    const int g = l >> 4, c = l & 15;
    const size_t hoff = (size_t)h * HD;
    ushort* sPh = &sP[w][0][0];
    ushort* sPl = &sP[w][1][0];

#define STAGE_KV(buf, kt_)                                                        \
  do {                                                                            \
    const int k0s = (kt_) * 64;                                                   \
    int cb0 = w * 64;                                                             \
    int ch0 = cb0 + l;                                                            \
    size_t kg0 = (size_t)(k0s + (ch0 & 63)) * D + hoff + (ch0 >> 6) * 8;          \
    size_t vg0 = (hoff + (ch0 & 63)) * (size_t)S + k0s + (ch0 >> 6) * 8;          \
    async_copy16(khp + kg0, &sK[buf][0][cb0 * 8]);                                \
    async_copy16(klp + kg0, &sK[buf][1][cb0 * 8]);                                \
    async_copy16(vth + vg0, &sV[buf][0][cb0 * 8]);                                \
    async_copy16(vtl + vg0, &sV[buf][1][cb0 * 8]);                                \
    int cb1 = 256 + w * 64;                                                       \
    int ch1 = cb1 + l;                                                            \
    size_t kg1 = (size_t)(k0s + (ch1 & 63)) * D + hoff + (ch1 >> 6) * 8;          \
    size_t vg1 = (hoff + (ch1 & 63)) * (size_t)S + k0s + (ch1 >> 6) * 8;          \
    async_copy16(khp + kg1, &sK[buf][0][cb1 * 8]);                                \
    async_copy16(klp + kg1, &sK[buf][1][cb1 * 8]);                                \
    async_copy16(vth + vg1, &sV[buf][0][cb1 * 8]);                                \
    async_copy16(vtl + vg1, &sV[buf][1][cb1 * 8]);                                \
  } while (0)

    // ---- Q fragments: A-layout direct from global (row = l&15, k = (l>>4)*8) ----
    const size_t qrow = (size_t)(qt * 64 + w * 16 + c) * D + hoff;
    bf16x8 aqh0 = *(const bf16x8*)(qhp + qrow + g * 8);
    bf16x8 aqh1 = *(const bf16x8*)(qhp + qrow + 32 + g * 8);
    bf16x8 aql0 = *(const bf16x8*)(qlp + qrow + g * 8);
    bf16x8 aql1 = *(const bf16x8*)(qlp + qrow + 32 + g * 8);

    STAGE_KV(0, 0);
    asm volatile("s_waitcnt vmcnt(0)" ::: "memory");
    __builtin_amdgcn_s_barrier();
    __builtin_amdgcn_sched_barrier(0);

    float m_[4], l_[4];
    f32x4 oacc[4];
#pragma unroll
    for (int r = 0; r < 4; r++) { m_[r] = -3e38f; l_[r] = 0.0f; }
#pragma unroll
    for (int fn = 0; fn < 4; fn++) oacc[fn] = (f32x4){0.f, 0.f, 0.f, 0.f};

    for (int kt = 0; kt <= qt; kt++) {
        const int cur = kt & 1;
        if (kt < qt) STAGE_KV(1 - cur, kt + 1);   // issue next tile early
        const ushort* sKh = &sK[cur][0][0];
        const ushort* sKl = &sK[cur][1][0];
        // ---- S = Q K^T (drop lo*lo) ----
        bf16x8 b0[4], b1[4], c0[4], c1[4];
#pragma unroll
        for (int fn = 0; fn < 4; fn++) {
            int u0 = (g * 64 + fn * 16 + c) * 8;
            int u1 = ((4 + g) * 64 + fn * 16 + c) * 8;
            b0[fn] = *(const bf16x8*)(sKh + u0);
            b1[fn] = *(const bf16x8*)(sKh + u1);
            c0[fn] = *(const bf16x8*)(sKl + u0);
            c1[fn] = *(const bf16x8*)(sKl + u1);
        }
        f32x4 sacc[4];
#pragma unroll
        for (int fn = 0; fn < 4; fn++) {
            f32x4 a = (f32x4){0.f, 0.f, 0.f, 0.f};
            a = __builtin_amdgcn_mfma_f32_16x16x32_bf16(aqh0, b0[fn], a, 0, 0, 0);
            a = __builtin_amdgcn_mfma_f32_16x16x32_bf16(aqh1, b1[fn], a, 0, 0, 0);
            a = __builtin_amdgcn_mfma_f32_16x16x32_bf16(aqh0, c0[fn], a, 0, 0, 0);
            a = __builtin_amdgcn_mfma_f32_16x16x32_bf16(aqh1, c1[fn], a, 0, 0, 0);
            a = __builtin_amdgcn_mfma_f32_16x16x32_bf16(aql0, b0[fn], a, 0, 0, 0);
            a = __builtin_amdgcn_mfma_f32_16x16x32_bf16(aql1, b1[fn], a, 0, 0, 0);
            sacc[fn] = a;
        }
        // ---- causal mask (diagonal tile only) ----
        if (kt == qt) {
#pragma unroll
            for (int fn = 0; fn < 4; fn++)
#pragma unroll
                for (int r = 0; r < 4; r++)
                    if (fn * 16 + c > w * 16 + g * 4 + r) sacc[fn][r] = -3e38f;
        }
        // ---- online softmax in exp2 domain ----
        float alpha[4];
#pragma unroll
        for (int r = 0; r < 4; r++) {
            float rm = fmaxf(fmaxf(sacc[0][r], sacc[1][r]), fmaxf(sacc[2][r], sacc[3][r]));
#pragma unroll
            for (int off = 1; off < 16; off <<= 1) rm = fmaxf(rm, __shfl_xor(rm, off));
            float mn = fmaxf(m_[r], rm);
            alpha[r] = exp2f(m_[r] - mn);
            m_[r] = mn;
            float rs = 0.0f;
#pragma unroll
            for (int fn = 0; fn < 4; fn++) {
                float pp = exp2f(sacc[fn][r] - mn);
                sacc[fn][r] = pp;
                rs += pp;
            }
#pragma unroll
            for (int off = 1; off < 16; off <<= 1) rs += __shfl_xor(rs, off);
            l_[r] = l_[r] * alpha[r] + rs;
        }
#pragma unroll
        for (int fn = 0; fn < 4; fn++)
#pragma unroll
            for (int r = 0; r < 4; r++) oacc[fn][r] *= alpha[r];
        // ---- P (C-layout) -> per-wave LDS (A-layout), hi/lo bf16 ----
#pragma unroll
        for (int fn = 0; fn < 4; fn++) {
            int chunk = fn * 2 + (c >> 3);
#pragma unroll
            for (int r = 0; r < 4; r++) {
                float pp = sacc[fn][r];
                ushort ph = f2bf(pp);
                int off = (chunk * 16 + g * 4 + r) * 8 + (c & 7);
                sPh[off] = ph;
                sPl[off] = f2bf(pp - bf2f(ph));
            }
        }
        // ---- O += P V (drop lo*lo) ----
        const ushort* sVh = &sV[cur][0][0];
        const ushort* sVl = &sV[cur][1][0];
        bf16x8 pa0 = *(const bf16x8*)(sPh + (g * 16 + c) * 8);
        bf16x8 pa1 = *(const bf16x8*)(sPh + ((4 + g) * 16 + c) * 8);
        bf16x8 pb0 = *(const bf16x8*)(sPl + (g * 16 + c) * 8);
        bf16x8 pb1 = *(const bf16x8*)(sPl + ((4 + g) * 16 + c) * 8);
#pragma unroll
        for (int fn = 0; fn < 4; fn++) {
            int u0 = (g * 64 + fn * 16 + c) * 8;
            int u1 = ((4 + g) * 64 + fn * 16 + c) * 8;
            bf16x8 vh0 = *(const bf16x8*)(sVh + u0);
            bf16x8 vh1 = *(const bf16x8*)(sVh + u1);
            bf16x8 vl0 = *(const bf16x8*)(sVl + u0);
            bf16x8 vl1 = *(const bf16x8*)(sVl + u1);
            f32x4 o = oacc[fn];
            o = __builtin_amdgcn_mfma_f32_16x16x32_bf16(pa0, vh0, o, 0, 0, 0);
            o = __builtin_amdgcn_mfma_f32_16x16x32_bf16(pa1, vh1, o, 0, 0, 0);
            o = __builtin_amdgcn_mfma_f32_16x16x32_bf16(pa0, vl0, o, 0, 0, 0);
            o = __builtin_amdgcn_mfma_f32_16x16x32_bf16(pa1, vl1, o, 0, 0, 0);
            o = __builtin_amdgcn_mfma_f32_16x16x32_bf16(pb0, vh0, o, 0, 0, 0);
            o = __builtin_amdgcn_mfma_f32_16x16x32_bf16(pb1, vh1, o, 0, 0, 0);
            oacc[fn] = o;
        }
        if (kt < qt) {
            asm volatile("s_waitcnt vmcnt(0)" ::: "memory");  // next tile staged
            __builtin_amdgcn_s_barrier();
            __builtin_amdgcn_sched_barrier(0);
        }
    }
    // ---- epilogue: normalize + store bf16x2 planes ----
#pragma unroll
    for (int r = 0; r < 4; r++) {
        float inv = 1.0f / l_[r];
        size_t orow = (size_t)(qt * 64 + w * 16 + g * 4 + r) * D + hoff;
#pragma unroll
        for (int fn = 0; fn < 4; fn++) {
            float v = oacc[fn][r] * inv;
            ushort hi = f2bf(v);
            oh_out[orow + fn * 16 + c] = hi;
            ol_out[orow + fn * 16 + c] = f2bf(v - bf2f(hi));
        }
    }
#undef STAGE_KV
}

// ============ Router (fp32 — routing must match reference exactly) ============
__global__ __launch_bounds__(64) void router_kernel(const float* __restrict__ x,
    const float* __restrict__ wr, int* __restrict__ ei, float* __restrict__ ew,
    int* __restrict__ counts, float* __restrict__ prob_sums, float* __restrict__ z_sum)
{
    int t = blockIdx.x, lane = threadIdx.x;
    const float* xr = x + (size_t)t * D;
    float p[E] = {};
    for (int d = lane; d < D; d += 64) {
        float xd = xr[d];
        const float* wrow = wr + d * E;
#pragma unroll
        for (int e = 0; e < E; e++) p[e] = fmaf(xd, wrow[e], p[e]);
    }
#pragma unroll
    for (int off = 32; off > 0; off >>= 1) {
#pragma unroll
        for (int e = 0; e < E; e++) p[e] += __shfl_xor(p[e], off);
    }
    float m = p[0];
#pragma unroll
    for (int e = 1; e < E; e++) m = fmaxf(m, p[e]);
    float sum = 0.0f, pr[E];
#pragma unroll
    for (int e = 0; e < E; e++) { pr[e] = expf(p[e] - m); sum += pr[e]; }
    float invs = 1.0f / sum;
#pragma unroll
    for (int e = 0; e < E; e++) pr[e] *= invs;
    float lse = m + logf(sum);
    int e1 = 0; float b1 = pr[0];
#pragma unroll
    for (int e = 1; e < E; e++) if (pr[e] > b1) { b1 = pr[e]; e1 = e; }
    int e2 = -1; float b2 = -1.0f;
#pragma unroll
    for (int e = 0; e < E; e++) if (e != e1 && pr[e] > b2) { b2 = pr[e]; e2 = e; }
    float wsum = b1 + b2;
    if (lane == 0) {
        ei[2 * t] = e1; ei[2 * t + 1] = e2;
        ew[2 * t] = b1 / wsum; ew[2 * t + 1] = b2 / wsum;
        atomicAdd(&counts[e1], 1);
        atomicAdd(&counts[e2], 1);
        atomicAdd(z_sum, lse * lse);
    }
    if (lane < E) atomicAdd(&prob_sums[lane], pr[lane]);
}

__global__ void zero_kernel(int* counts, float* prob_sums, float* z_sum)
{
    int tid = threadIdx.x;
    if (tid < E) { counts[tid] = 0; prob_sums[tid] = 0.0f; }
    if (tid == 0) *z_sum = 0.0f;
}

__global__ void finalize_kernel(const int* __restrict__ counts, const float* __restrict__ prob_sums,
    const float* __restrict__ z_sum, int* __restrict__ offs, int* __restrict__ cursor,
    float* __restrict__ aux_out)
{
    if (threadIdx.x == 0) {
        int off = 0;
        for (int e = 0; e < E; e++) { offs[e] = off; cursor[e] = off; off += counts[e]; }
        float z = 1e-3f * (*z_sum) * (1.0f / S);
        float lb = 0.0f;
        for (int e = 0; e < E; e++) lb += ((float)counts[e] / (float)S) * (prob_sums[e] / (float)S);
        lb *= 1e-2f;
        *aux_out = z + lb;
    }
}

__global__ __launch_bounds__(256) void scatter_kernel(const int* __restrict__ ei,
    int* __restrict__ cursor, int* __restrict__ tlist, int* __restrict__ slot_of)
{
    int t = blockIdx.x * 256 + threadIdx.x;
    if (t >= S) return;
#pragma unroll
    for (int kk = 0; kk < 2; kk++) {
        int e = ei[2 * t + kk];
        int slot = atomicAdd(&cursor[e], 1);
        tlist[slot] = t;
        slot_of[2 * t + kk] = slot;
    }
}

__global__ __launch_bounds__(256) void gather_kernel(const ushort* __restrict__ xbf,
    const int* __restrict__ tlist, ushort* __restrict__ xg)
{
    int slot = blockIdx.x;
    int t4 = threadIdx.x * 4;
    ushort4 vv;
    if (slot < NSLOTS) {
        int tok = tlist[slot];
        vv = *(const ushort4*)(xbf + (size_t)tok * D + t4);
    } else {
        vv = make_ushort4(0, 0, 0, 0);
    }
    *(ushort4*)(xg + (size_t)slot * D + t4) = vv;
}

// ============ MoE gate+up GEMM, N-concat over [gate|up], BK=32, depth-2 pipeline ============
__global__ __launch_bounds__(256) void moe_gateup_mfma(const ushort* __restrict__ xg,
    const ushort* __restrict__ wgt, const ushort* __restrict__ wut,
    ushort* __restrict__ Hg, ushort* __restrict__ Hu,
    const int* __restrict__ offs, const int* __restrict__ cnts)
{
    const int e = blockIdx.z;
    const int cnt = cnts[e];
    const int m0 = blockIdx.y * 128;
    if (m0 >= cnt) return;
    const int off = offs[e];
    const int n0g = blockIdx.x * 128;   // over concat 2F
    const bool isg = n0g < F;
    const ushort* Wt = isg ? (wgt + (size_t)e * F * D + (size_t)n0g * D)
                           : (wut + (size_t)e * F * D + (size_t)(n0g - F) * D);
    ushort* Outp = isg ? Hg : Hu;
    const int ncol0 = isg ? n0g : n0g - F;
    __shared__ ushort As[3][4096], Ws[3][4096];
    const int tid = threadIdx.x;
    const int w = tid >> 6, l = tid & 63;
    const int wm = (w >> 1) * 64, wn = (w & 1) * 64;
    const int kc = l >> 4, lr = l & 15;
    const ushort* Arow = xg + (size_t)(off + m0) * D;

#define STAGE_GU(buf, t_)                                                     \
  do {                                                                        \
    int kbase = (t_) * 32;                                                    \
    _Pragma("unroll")                                                         \
    for (int it = 0; it < 2; it++) {                                          \
      int cch = it * 256 + tid;                                               \
      int ckc = cch >> 7, r = cch & 127;                                      \
      int loff = (it * 256 + w * 64) * 8;                                     \
      async_copy16(Arow + (size_t)r * D + kbase + ckc * 8, As[buf] + loff);   \
      async_copy16(Wt   + (size_t)r * D + kbase + ckc * 8, Ws[buf] + loff);   \
    }                                                                         \
  } while (0)

    f32x4 acc[4][4];
#pragma unroll
    for (int i = 0; i < 4; i++)
#pragma unroll
        for (int j = 0; j < 4; j++) acc[i][j] = (f32x4){0.f, 0.f, 0.f, 0.f};

    const int NT = D / 32;   // 32
    STAGE_GU(0, 0);
    STAGE_GU(1, 1);
    for (int t = 0; t < NT; ++t) {
        const int cur = t % 3;
        if (t + 1 < NT) { asm volatile("s_waitcnt vmcnt(4)" ::: "memory"); }
        else            { asm volatile("s_waitcnt vmcnt(0)" ::: "memory"); }
        __builtin_amdgcn_s_barrier();
        __builtin_amdgcn_sched_barrier(0);
        if (t + 2 < NT) STAGE_GU((t + 2) % 3, t + 2);
        bf16x8 af[4], wf[4];
#pragma unroll
        for (int f = 0; f < 4; f++) {
            af[f] = *(const bf16x8*)(As[cur] + (kc * 128 + wm + f * 16 + lr) * 8);
            wf[f] = *(const bf16x8*)(Ws[cur] + (kc * 128 + wn + f * 16 + lr) * 8);
        }
#pragma unroll
        for (int fm = 0; fm < 4; fm++)
#pragma unroll
            for (int fn = 0; fn < 4; fn++)
                acc[fm][fn] = __builtin_amdgcn_mfma_f32_16x16x32_bf16(af[fm], wf[fn], acc[fm][fn], 0, 0, 0);
    }
#undef STAGE_GU
#pragma unroll
    for (int fm = 0; fm < 4; fm++)
#pragma unroll
        for (int fn = 0; fn < 4; fn++)
#pragma unroll
            for (int r = 0; r < 4; r++) {
                int rloc = m0 + wm + fm * 16 + (l >> 4) * 4 + r;
                if (rloc < cnt) {
                    int col = ncol0 + wn + fn * 16 + (l & 15);
                    Outp[(size_t)(off + rloc) * F + col] = f2bf(acc[fm][fn][r]);
                }
            }
}

// ============ SiLU(g)*u elementwise ============
__global__ __launch_bounds__(256) void silu_kernel(const ushort* __restrict__ Gout,
    const ushort* __restrict__ Uout, ushort* __restrict__ Hb)
{
    int slot = blockIdx.x;
    int f0 = threadIdx.x * 8;
    bf16x8 gv = *(const bf16x8*)(Gout + (size_t)slot * F + f0);
    bf16x8 uv = *(const bf16x8*)(Uout + (size_t)slot * F + f0);
    bf16x8 o;
#pragma unroll
    for (int j = 0; j < 8; j++) {
        float g = bf2f((ushort)gv[j]);
        float u = bf2f((ushort)uv[j]);
        o[j] = (short)f2bf(g / (1.0f + expf(-g)) * u);
    }
    *(bf16x8*)(Hb + (size_t)slot * F + f0) = o;
}

// ============ MoE down GEMM (BK=32, depth-2 pipeline) ============
__global__ __launch_bounds__(256) void moe_down_mfma(const ushort* __restrict__ Hb,
    const ushort* __restrict__ wdt, ushort* __restrict__ yb,
    const int* __restrict__ offs, const int* __restrict__ cnts)
{
    const int e = blockIdx.z;
    const int cnt = cnts[e];
    const int m0 = blockIdx.y * 128;
    if (m0 >= cnt) return;
    const int off = offs[e];
    const ushort* Bt = wdt + (size_t)e * D * F;
    const int n0 = blockIdx.x * 128;
    __shared__ ushort As[3][4096], Bs[3][4096];
    const int tid = threadIdx.x;
    const int w = tid >> 6, l = tid & 63;
    const int wm = (w >> 1) * 64, wn = (w & 1) * 64;
    const int kc = l >> 4, lr = l & 15;
    const ushort* Arow = Hb + (size_t)(off + m0) * F;
    const ushort* Brow = Bt + (size_t)n0 * F;

#define STAGE_DN(buf, t_)                                                     \
  do {                                                                        \
    int kbase = (t_) * 32;                                                    \
    _Pragma("unroll")                                                         \
    for (int it = 0; it < 2; it++) {                                          \
      int cch = it * 256 + tid;                                               \
      int ckc = cch >> 7, r = cch & 127;                                      \
      int loff = (it * 256 + w * 64) * 8;                                     \
      async_copy16(Arow + (size_t)r * F + kbase + ckc * 8, As[buf] + loff);   \
      async_copy16(Brow + (size_t)r * F + kbase + ckc * 8, Bs[buf] + loff);   \
    }                                                                         \
  } while (0)

    f32x4 acc[4][4];
#pragma unroll
    for (int i = 0; i < 4; i++)
#pragma unroll
        for (int j = 0; j < 4; j++) acc[i][j] = (f32x4){0.f,0.f,0.f,0.f};

    const int NT = F / 32;   // 64
    STAGE_DN(0, 0);
    STAGE_DN(1, 1);
    for (int t = 0; t < NT; ++t) {
        const int cur = t % 3;
        if (t + 1 < NT) { asm volatile("s_waitcnt vmcnt(4)" ::: "memory"); }
        else            { asm volatile("s_waitcnt vmcnt(0)" ::: "memory"); }
        __builtin_amdgcn_s_barrier();
        __builtin_amdgcn_sched_barrier(0);
        if (t + 2 < NT) STAGE_DN((t + 2) % 3, t + 2);
        bf16x8 af[4], bfr[4];
#pragma unroll
        for (int f = 0; f < 4; f++) {
            af[f]  = *(const bf16x8*)(As[cur] + (kc * 128 + wm + f * 16 + lr) * 8);
            bfr[f] = *(const bf16x8*)(Bs[cur] + (kc * 128 + wn + f * 16 + lr) * 8);
        }
#pragma unroll
        for (int fm = 0; fm < 4; fm++)
#pragma unroll
            for (int fn = 0; fn < 4; fn++)
                acc[fm][fn] = __builtin_amdgcn_mfma_f32_16x16x32_bf16(af[fm], bfr[fn], acc[fm][fn], 0, 0, 0);
    }
#undef STAGE_DN
#pragma unroll
    for (int fm = 0; fm < 4; fm++)
#pragma unroll
        for (int fn = 0; fn < 4; fn++)
#pragma unroll
            for (int r = 0; r < 4; r++) {
                int rloc = m0 + wm + fm * 16 + (l >> 4) * 4 + r;
                if (rloc < cnt) {
                    int col = n0 + wn + fn * 16 + (l & 15);
                    yb[(size_t)(off + rloc) * D + col] = f2bf(acc[fm][fn][r]);
                }
            }
}

// ============ Combine ============
__global__ __launch_bounds__(256) void combine_kernel(const float* __restrict__ hs2,
    const ushort* __restrict__ yb, const float* __restrict__ ew,
    const int* __restrict__ slot_of, float* __restrict__ out)
{
    int t = blockIdx.x, tid = threadIdx.x;
    int s0 = slot_of[2 * t], s1 = slot_of[2 * t + 1];
    float w0 = ew[2 * t], w1 = ew[2 * t + 1];
    float4 a = *(const float4*)(hs2 + (size_t)t * D + tid * 4);
    ushort4 y0 = *(const ushort4*)(yb + (size_t)s0 * D + tid * 4);
    ushort4 y1 = *(const ushort4*)(yb + (size_t)s1 * D + tid * 4);
    float4 o;
    o.x = a.x + w0 * bf2f(y0.x) + w1 * bf2f(y1.x);
    o.y = a.y + w0 * bf2f(y0.y) + w1 * bf2f(y1.y);
    o.z = a.z + w0 * bf2f(y0.z) + w1 * bf2f(y1.z);
    o.w = a.w + w0 * bf2f(y0.w) + w1 * bf2f(y1.w);
    *(float4*)(out + (size_t)t * D + tid * 4) = o;
}

// ============ launch ============
extern "C" void kernel_launch(void* const* d_in, const int* in_sizes, int n_in,
                              void* d_out, int out_size, void* d_ws, size_t ws_size,
                              hipStream_t stream)
{
    (void)in_sizes; (void)n_in; (void)out_size; (void)ws_size;
    const float* hs   = (const float*)d_in[0];
    const float* ln1w = (const float*)d_in[3];
    const float* ln1b = (const float*)d_in[4];
    const float* ln2w = (const float*)d_in[5];
    const float* ln2b = (const float*)d_in[6];
    const float* wq   = (const float*)d_in[7];
    const float* wk   = (const float*)d_in[8];
    const float* wv   = (const float*)d_in[9];
    const float* wo   = (const float*)d_in[10];
    const float* wr   = (const float*)d_in[11];
    const float* wg   = (const float*)d_in[12];
    const float* wu   = (const float*)d_in[13];
    const float* wd   = (const float*)d_in[14];
    float* out = (float*)d_out;

    const size_t TD = (size_t)S * D;
    char* p = (char*)d_ws;
    auto alloc = [&](size_t bytes) { char* r = p; p += (bytes + 255) & ~(size_t)255; return r; };

    ushort* wgt  = (ushort*)alloc((size_t)E * D * F * 2);
    ushort* wut  = (ushort*)alloc((size_t)E * D * F * 2);
    ushort* wdt  = (ushort*)alloc((size_t)E * D * F * 2);
    ushort* wqh  = (ushort*)alloc((size_t)D * D * 2);
    ushort* wqlo = (ushort*)alloc((size_t)D * D * 2);
    ushort* wkh  = (ushort*)alloc((size_t)D * D * 2);
    ushort* wklo = (ushort*)alloc((size_t)D * D * 2);
    ushort* wvh  = (ushort*)alloc((size_t)D * D * 2);
    ushort* wvlo = (ushort*)alloc((size_t)D * D * 2);
    ushort* woh  = (ushort*)alloc((size_t)D * D * 2);
    ushort* wolo = (ushort*)alloc((size_t)D * D * 2);
    ushort* xh   = (ushort*)alloc(TD * 2);
    ushort* xl   = (ushort*)alloc(TD * 2);
    float*  qb   = (float*)alloc(TD * 4);   // fp32 Q; later: Gout = qb..kb (16.78 MB)
    float*  kb   = (float*)alloc(TD * 4);
    float*  vb   = (float*)alloc(TD * 4);   // fp32 V; later: Uout = vb..atl (16.78 MB)
    ushort* ath  = (ushort*)alloc(TD * 2);
    ushort* atl  = (ushort*)alloc(TD * 2);
    float*  hs2  = (float*)alloc(TD * 4);
    float*  xf32 = (float*)alloc(TD * 4);
    ushort* xbf  = (ushort*)alloc(TD * 2);
    ushort* xg   = (ushort*)alloc((size_t)NPAD * D * 2);
    ushort* Hb   = (ushort*)alloc((size_t)NPAD * F * 2);
    ushort* yb   = (ushort*)alloc((size_t)NPAD * D * 2);
    ushort* khp  = (ushort*)alloc(TD * 2);   // K bf16 hi (post-rope), row-major [S][D]
    ushort* klp  = (ushort*)alloc(TD * 2);   // K bf16 lo
    ushort* vth  = (ushort*)alloc(TD * 2);   // V^T bf16 hi, [D][S]
    ushort* vtl  = (ushort*)alloc(TD * 2);   // V^T bf16 lo
    float*  ewb       = (float*)alloc(2 * S * 4);
    float*  prob_sums = (float*)alloc(8 * 4);
    float*  z_sum     = (float*)alloc(8 * 4);
    int* ei      = (int*)alloc(2 * S * 4);
    int* slot_of = (int*)alloc(2 * S * 4);
    int* tlist   = (int*)alloc(NSLOTS * 4);
    int* counts  = (int*)alloc(8 * 4);
    int* offs    = (int*)alloc(8 * 4);
    int* cursor  = (int*)alloc(8 * 4);

    // Raw gate/up GEMM outputs alias dead attention fp32 buffers (exact-size fit):
    ushort* Gout = (ushort*)qb;
    ushort* Uout = (ushort*)vb;

    // ---- weight prep ----
    castT2_kernel<<<dim3(D / 64, D / 64, 1), 256, 0, stream>>>(wq, wqh, wqlo, D, D);
    castT2_kernel<<<dim3(D / 64, D / 64, 1), 256, 0, stream>>>(wk, wkh, wklo, D, D);
    castT2_kernel<<<dim3(D / 64, D / 64, 1), 256, 0, stream>>>(wv, wvh, wvlo, D, D);
    castT2_kernel<<<dim3(D / 64, D / 64, 1), 256, 0, stream>>>(wo, woh, wolo, D, D);
    castT_kernel<<<dim3(F / 64, D / 64, E), 256, 0, stream>>>(wg, wgt, D, F);
    castT_kernel<<<dim3(F / 64, D / 64, E), 256, 0, stream>>>(wu, wut, D, F);
    castT_kernel<<<dim3(D / 64, F / 64, E), 256, 0, stream>>>(wd, wdt, F, D);

    // ---- attention sub-block ----
    ln_kernel<<<S, 256, 0, stream>>>(hs, ln1w, ln1b, nullptr, xh, xl);
    qkv_mfma2<<<dim3(D / 128, S / 128, 3), 256, 0, stream>>>(xh, xl, wqh, wqlo, wkh, wklo, wvh, wvlo, qb, kb, vb);
    rope_cast<<<S, 512, 0, stream>>>(qb, kb, xh, xl, khp, klp);
    castT2_kernel<<<dim3(D / 64, S / 64, 1), 256, 0, stream>>>(vb, vth, vtl, S, D);
    attn_mfma<<<dim3(32, 16), 256, 0, stream>>>(xh, xl, khp, klp, vth, vtl, ath, atl);
    wo_mfma2<<<dim3(D / 128, S / 128), 256, 0, stream>>>(ath, atl, woh, wolo, hs, hs2);

    // ---- MoE sub-block ----
    ln_kernel<<<S, 256, 0, stream>>>(hs2, ln2w, ln2b, xf32, xbf, nullptr);
    zero_kernel<<<1, 64, 0, stream>>>(counts, prob_sums, z_sum);
    router_kernel<<<S, 64, 0, stream>>>(xf32, wr, ei, ewb, counts, prob_sums, z_sum);
    finalize_kernel<<<1, 64, 0, stream>>>(counts, prob_sums, z_sum, offs, cursor, out + TD);
    scatter_kernel<<<S / 256, 256, 0, stream>>>(ei, cursor, tlist, slot_of);
    gather_kernel<<<NPAD, 256, 0, stream>>>(xbf, tlist, xg);
    moe_gateup_mfma<<<dim3(2 * F / 128, NSLOTS / 128, E), 256, 0, stream>>>(xg, wgt, wut, Gout, Uout, offs, counts);
    silu_kernel<<<NSLOTS, 256, 0, stream>>>(Gout, Uout, Hb);
    moe_down_mfma<<<dim3(D / 128, NSLOTS / 128, E), 256, 0, stream>>>(Hb, wdt, yb, offs, counts);
    combine_kernel<<<S, 256, 0, stream>>>(hs2, yb, ewb, slot_of, out);
}

// Round 5
// 862.107 us; speedup vs baseline: 1.0078x; 1.0078x over previous
//
#include <hip/hip_runtime.h>
#include <math.h>

static constexpr int S = 2048;          // tokens (B=1)
static constexpr int D = 1024;          // model dim
static constexpr int H = 16;            // heads
static constexpr int HD = 64;           // head dim
static constexpr int E = 8;             // experts
static constexpr int F = 2048;          // ffn dim
static constexpr int NSLOTS = S * 2;    // 4096
static constexpr int NPAD = NSLOTS + 128;

typedef __attribute__((ext_vector_type(8))) short bf16x8;
typedef __attribute__((ext_vector_type(4))) float f32x4;

__device__ __forceinline__ float bf2f(ushort u) {
    uint32_t x = ((uint32_t)u) << 16; float f; __builtin_memcpy(&f, &x, 4); return f;
}
__device__ __forceinline__ ushort f2bf(float f) {
    uint32_t x; __builtin_memcpy(&x, &f, 4);
    return (ushort)((x + 0x7fffu + ((x >> 16) & 1u)) >> 16);
}
__device__ __forceinline__ void async_copy16(const void* gptr, void* ldsptr) {
    __builtin_amdgcn_global_load_lds(
        (const __attribute__((address_space(1))) void*)gptr,
        (__attribute__((address_space(3))) void*)ldsptr, 16, 0, 0);
}

// ============ cast + transpose fp32 [K][N] -> bf16 [N][K] (single plane, MoE weights) ============
__global__ __launch_bounds__(256) void castT_kernel(const float* __restrict__ src,
    ushort* __restrict__ dst, int K, int N)
{
    __shared__ float T[64][65];
    int z = blockIdx.z;
    src += (size_t)z * K * N; dst += (size_t)z * K * N;
    int k0 = blockIdx.y * 64, n0 = blockIdx.x * 64;
    int t = threadIdx.x;
    int r = t >> 4, c4 = (t & 15) * 4;
#pragma unroll
    for (int it = 0; it < 4; it++) {
        float4 v = *(const float4*)(src + (size_t)(k0 + r + it * 16) * N + n0 + c4);
        T[r + it * 16][c4 + 0] = v.x; T[r + it * 16][c4 + 1] = v.y;
        T[r + it * 16][c4 + 2] = v.z; T[r + it * 16][c4 + 3] = v.w;
    }
    __syncthreads();
#pragma unroll
    for (int it = 0; it < 4; it++) {
        int rr = r + it * 16;
        ushort4 o;
        o.x = f2bf(T[c4 + 0][rr]); o.y = f2bf(T[c4 + 1][rr]);
        o.z = f2bf(T[c4 + 2][rr]); o.w = f2bf(T[c4 + 3][rr]);
        *(ushort4*)(dst + (size_t)(n0 + rr) * K + k0 + c4) = o;
    }
}

// ============ cast + transpose fp32 [K][N] -> bf16x2 hi/lo planes [N][K] ============
__global__ __launch_bounds__(256) void castT2_kernel(const float* __restrict__ src,
    ushort* __restrict__ dh, ushort* __restrict__ dl, int K, int N)
{
    __shared__ float T[64][65];
    src += (size_t)blockIdx.z * K * N;
    dh += (size_t)blockIdx.z * K * N; dl += (size_t)blockIdx.z * K * N;
    int k0 = blockIdx.y * 64, n0 = blockIdx.x * 64;
    int t = threadIdx.x;
    int r = t >> 4, c4 = (t & 15) * 4;
#pragma unroll
    for (int it = 0; it < 4; it++) {
        float4 v = *(const float4*)(src + (size_t)(k0 + r + it * 16) * N + n0 + c4);
        T[r + it * 16][c4 + 0] = v.x; T[r + it * 16][c4 + 1] = v.y;
        T[r + it * 16][c4 + 2] = v.z; T[r + it * 16][c4 + 3] = v.w;
    }
    __syncthreads();
#pragma unroll
    for (int it = 0; it < 4; it++) {
        int rr = r + it * 16;
        ushort4 oh, ol;
        float v0 = T[c4 + 0][rr], v1 = T[c4 + 1][rr], v2 = T[c4 + 2][rr], v3 = T[c4 + 3][rr];
        oh.x = f2bf(v0); ol.x = f2bf(v0 - bf2f(oh.x));
        oh.y = f2bf(v1); ol.y = f2bf(v1 - bf2f(oh.y));
        oh.z = f2bf(v2); ol.z = f2bf(v2 - bf2f(oh.z));
        oh.w = f2bf(v3); ol.w = f2bf(v3 - bf2f(oh.w));
        *(ushort4*)(dh + (size_t)(n0 + rr) * K + k0 + c4) = oh;
        *(ushort4*)(dl + (size_t)(n0 + rr) * K + k0 + c4) = ol;
    }
}

// ============ LayerNorm: optional fp32 / bf16-hi / bf16-lo outputs ============
__global__ __launch_bounds__(256) void ln_kernel(const float* __restrict__ x,
    const float* __restrict__ w, const float* __restrict__ b,
    float* __restrict__ yf, ushort* __restrict__ yh, ushort* __restrict__ yl)
{
    int t = blockIdx.x, tid = threadIdx.x;
    __shared__ float redx[256];
    __shared__ float redy[256];
    const float* xr = x + (size_t)t * D;
    float4 xv = *(const float4*)(xr + tid * 4);
    redx[tid] = xv.x + xv.y + xv.z + xv.w;
    redy[tid] = xv.x * xv.x + xv.y * xv.y + xv.z * xv.z + xv.w * xv.w;
    __syncthreads();
    for (int st = 128; st > 0; st >>= 1) {
        if (tid < st) { redx[tid] += redx[tid + st]; redy[tid] += redy[tid + st]; }
        __syncthreads();
    }
    float mean = redx[0] * (1.0f / D);
    float var  = redy[0] * (1.0f / D) - mean * mean;
    float rstd = rsqrtf(var + 1e-5f);
    float4 wv = *(const float4*)(w + tid * 4);
    float4 bv = *(const float4*)(b + tid * 4);
    float4 o;
    o.x = (xv.x - mean) * rstd * wv.x + bv.x;
    o.y = (xv.y - mean) * rstd * wv.y + bv.y;
    o.z = (xv.z - mean) * rstd * wv.z + bv.z;
    o.w = (xv.w - mean) * rstd * wv.w + bv.w;
    if (yf) *(float4*)(yf + (size_t)t * D + tid * 4) = o;
    ushort4 oh;
    oh.x = f2bf(o.x); oh.y = f2bf(o.y); oh.z = f2bf(o.z); oh.w = f2bf(o.w);
    if (yh) *(ushort4*)(yh + (size_t)t * D + tid * 4) = oh;
    if (yl) {
        ushort4 ol;
        ol.x = f2bf(o.x - bf2f(oh.x)); ol.y = f2bf(o.y - bf2f(oh.y));
        ol.z = f2bf(o.z - bf2f(oh.z)); ol.w = f2bf(o.w - bf2f(oh.w));
        *(ushort4*)(yl + (size_t)t * D + tid * 4) = ol;
    }
}

// ============ RoPE + bf16 hi/lo cast. Q pre-scaled by 0.125*log2(e) for exp2-softmax ============
__global__ __launch_bounds__(512) void rope_cast(const float* __restrict__ q,
    const float* __restrict__ k, ushort* __restrict__ qh, ushort* __restrict__ ql,
    ushort* __restrict__ kh, ushort* __restrict__ kl)
{
    int t = blockIdx.x;
    int idx = threadIdx.x;
    int hh = idx >> 5, i = idx & 31;
    float invf = powf(10000.0f, -(float)i / 32.0f);
    float ang = (float)t * invf;
    float cc = cosf(ang), ss = sinf(ang);
    size_t base = (size_t)t * D + hh * HD + i;
    const float QS = 0.125f * 1.4426950408889634f;
    float q1 = q[base], q2 = q[base + 32];
    float qr1 = (q1 * cc - q2 * ss) * QS;
    float qr2 = (q2 * cc + q1 * ss) * QS;
    ushort h1 = f2bf(qr1); qh[base] = h1;      ql[base] = f2bf(qr1 - bf2f(h1));
    ushort h2 = f2bf(qr2); qh[base + 32] = h2; ql[base + 32] = f2bf(qr2 - bf2f(h2));
    float k1 = k[base], k2 = k[base + 32];
    float kr1 = k1 * cc - k2 * ss;
    float kr2 = k2 * cc + k1 * ss;
    ushort h3 = f2bf(kr1); kh[base] = h3;      kl[base] = f2bf(kr1 - bf2f(h3));
    ushort h4 = f2bf(kr2); kh[base + 32] = h4; kl[base + 32] = f2bf(kr2 - bf2f(h4));
}

// ============ bf16x2 (fp32-emulated) MFMA k-loop: 64x128 tile, BK=32 ============
// 4 waves, wave tile 32x64 (acc[2][4]). Depth-1 pipelined; block co-residency
// (48 KB LDS -> 3 blocks/CU) supplies the cross-stall overlap.
__device__ __forceinline__ void stage_m2(const ushort* __restrict__ Ah_g,
    const ushort* __restrict__ Al_g, const ushort* __restrict__ Bh_g,
    const ushort* __restrict__ Bl_g, int lda, int ldb, int kbase,
    ushort* sAh, ushort* sAl, ushort* sBh, ushort* sBl, int tid, int w)
{
    {
        int ckc = tid >> 6, r = tid & 63;
        int loff = (w * 64) * 8;
        size_t ga = (size_t)r * lda + kbase + ckc * 8;
        async_copy16(Ah_g + ga, sAh + loff);
        async_copy16(Al_g + ga, sAl + loff);
    }
#pragma unroll
    for (int it = 0; it < 2; it++) {
        int c = it * 256 + tid;
        int ckc = c >> 7, r = c & 127;
        int loff = (it * 256 + w * 64) * 8;
        size_t gb = (size_t)r * ldb + kbase + ckc * 8;
        async_copy16(Bh_g + gb, sBh + loff);
        async_copy16(Bl_g + gb, sBl + loff);
    }
}

__device__ __forceinline__ void mfma2_kloop(const ushort* __restrict__ Ah_g,
    const ushort* __restrict__ Al_g, const ushort* __restrict__ Bh_g,
    const ushort* __restrict__ Bl_g, int lda, int ldb, int K,
    ushort (&sAh)[2][2048], ushort (&sAl)[2][2048],
    ushort (&sBh)[2][4096], ushort (&sBl)[2][4096], f32x4 (&acc)[2][4])
{
    const int tid = threadIdx.x;
    const int w = tid >> 6, l = tid & 63;
    const int wm = (w >> 1) * 32, wn = (w & 1) * 64;
    const int kc = l >> 4, lr = l & 15;
    const int NT = K / 32;
    stage_m2(Ah_g, Al_g, Bh_g, Bl_g, lda, ldb, 0, sAh[0], sAl[0], sBh[0], sBl[0], tid, w);
    for (int t = 0; t < NT; ++t) {
        const int cur = t & 1;
        asm volatile("s_waitcnt vmcnt(0)" ::: "memory");
        __builtin_amdgcn_s_barrier();
        __builtin_amdgcn_sched_barrier(0);
        if (t + 1 < NT)
            stage_m2(Ah_g, Al_g, Bh_g, Bl_g, lda, ldb, (t + 1) * 32,
                     sAh[1 - cur], sAl[1 - cur], sBh[1 - cur], sBl[1 - cur], tid, w);
        bf16x8 ah[2], al[2], bh[4], bl[4];
#pragma unroll
        for (int f = 0; f < 2; f++) {
            int ao = (kc * 64 + wm + f * 16 + lr) * 8;
            ah[f] = *(const bf16x8*)(sAh[cur] + ao);
            al[f] = *(const bf16x8*)(sAl[cur] + ao);
        }
#pragma unroll
        for (int f = 0; f < 4; f++) {
            int bo = (kc * 128 + wn + f * 16 + lr) * 8;
            bh[f] = *(const bf16x8*)(sBh[cur] + bo);
            bl[f] = *(const bf16x8*)(sBl[cur] + bo);
        }
#pragma unroll
        for (int fm = 0; fm < 2; fm++)
#pragma unroll
            for (int fn = 0; fn < 4; fn++) {
                acc[fm][fn] = __builtin_amdgcn_mfma_f32_16x16x32_bf16(ah[fm], bh[fn], acc[fm][fn], 0, 0, 0);
                acc[fm][fn] = __builtin_amdgcn_mfma_f32_16x16x32_bf16(ah[fm], bl[fn], acc[fm][fn], 0, 0, 0);
                acc[fm][fn] = __builtin_amdgcn_mfma_f32_16x16x32_bf16(al[fm], bh[fn], acc[fm][fn], 0, 0, 0);
            }
    }
}

// ============ QKV GEMM bf16x2 -> fp32 out (z selects q/k/v) ============
__global__ __launch_bounds__(256) void qkv_mfma2(const ushort* __restrict__ xh,
    const ushort* __restrict__ xl,
    const ushort* __restrict__ wqh, const ushort* __restrict__ wql,
    const ushort* __restrict__ wkh, const ushort* __restrict__ wkl,
    const ushort* __restrict__ wvh, const ushort* __restrict__ wvl,
    float* __restrict__ qo, float* __restrict__ ko, float* __restrict__ vo)
{
    __shared__ ushort sAh[2][2048], sAl[2][2048], sBh[2][4096], sBl[2][4096];
    const ushort* Bh = blockIdx.z == 0 ? wqh : (blockIdx.z == 1 ? wkh : wvh);
    const ushort* Bl = blockIdx.z == 0 ? wql : (blockIdx.z == 1 ? wkl : wvl);
    float* C = blockIdx.z == 0 ? qo : (blockIdx.z == 1 ? ko : vo);
    int m0 = blockIdx.y * 64, n0 = blockIdx.x * 128;
    f32x4 acc[2][4];
#pragma unroll
    for (int i = 0; i < 2; i++)
#pragma unroll
        for (int j = 0; j < 4; j++) acc[i][j] = (f32x4){0.f, 0.f, 0.f, 0.f};
    mfma2_kloop(xh + (size_t)m0 * D, xl + (size_t)m0 * D,
                Bh + (size_t)n0 * D, Bl + (size_t)n0 * D, D, D, D,
                sAh, sAl, sBh, sBl, acc);
    const int l = threadIdx.x & 63, w = threadIdx.x >> 6;
    const int wm = (w >> 1) * 32, wn = (w & 1) * 64;
#pragma unroll
    for (int fm = 0; fm < 2; fm++)
#pragma unroll
        for (int fn = 0; fn < 4; fn++)
#pragma unroll
            for (int r = 0; r < 4; r++) {
                int row = m0 + wm + fm * 16 + (l >> 4) * 4 + r;
                int col = n0 + wn + fn * 16 + (l & 15);
                C[(size_t)row * D + col] = acc[fm][fn][r];
            }
}

// ============ WO GEMM bf16x2 + residual -> fp32 ============
__global__ __launch_bounds__(256) void wo_mfma2(const ushort* __restrict__ ah,
    const ushort* __restrict__ al, const ushort* __restrict__ wh, const ushort* __restrict__ wl,
    const float* __restrict__ resid, float* __restrict__ Cout)
{
    __shared__ ushort sAh[2][2048], sAl[2][2048], sBh[2][4096], sBl[2][4096];
    int m0 = blockIdx.y * 64, n0 = blockIdx.x * 128;
    f32x4 acc[2][4];
#pragma unroll
    for (int i = 0; i < 2; i++)
#pragma unroll
        for (int j = 0; j < 4; j++) acc[i][j] = (f32x4){0.f, 0.f, 0.f, 0.f};
    mfma2_kloop(ah + (size_t)m0 * D, al + (size_t)m0 * D,
                wh + (size_t)n0 * D, wl + (size_t)n0 * D, D, D, D,
                sAh, sAl, sBh, sBl, acc);
    const int l = threadIdx.x & 63, w = threadIdx.x >> 6;
    const int wm = (w >> 1) * 32, wn = (w & 1) * 64;
#pragma unroll
    for (int fm = 0; fm < 2; fm++)
#pragma unroll
        for (int fn = 0; fn < 4; fn++)
#pragma unroll
            for (int r = 0; r < 4; r++) {
                int row = m0 + wm + fm * 16 + (l >> 4) * 4 + r;
                int col = n0 + wn + fn * 16 + (l & 15);
                Cout[(size_t)row * D + col] = acc[fm][fn][r] + resid[(size_t)row * D + col];
            }
}

// ============ Flash attention via MFMA (bf16x2 triple-product QK^T and PV) ============
// Grid: (32, 16) = 512 blocks, one 64-row q-tile each -> 2 blocks/CU (80 KB LDS).
// XCD-aware bijective swizzle: wgid = (n&7)*64 + n>>3 gives each XCD 2 heads
// (K/V 2 MB fits 4 MB L2); within an XCD launch order walks qt 31->0 (LPT).
__global__ __launch_bounds__(256) void attn_mfma(
    const ushort* __restrict__ qhp, const ushort* __restrict__ qlp,
    const ushort* __restrict__ khp, const ushort* __restrict__ klp,
    const ushort* __restrict__ vth, const ushort* __restrict__ vtl,
    ushort* __restrict__ oh_out, ushort* __restrict__ ol_out)
{
    __shared__ ushort sK[2][2][4096];   // [buf][hi/lo][kc*64+ktok][8]  32 KB
    __shared__ ushort sV[2][2][4096];   // [buf][hi/lo][kc*64+hd][8]    32 KB
    __shared__ ushort sP[4][2][1024];   // [wave][hi/lo][chunk*16+row][8] 16 KB
    const int n = blockIdx.y * 32 + blockIdx.x;
    const int wg = ((n & 7) << 6) + (n >> 3);   // bijective 512-block XCD swizzle
    const int h = wg >> 5;
    const int qt = 31 - (wg & 31);              // big q-tiles dispatch first (LPT)
    const int tid = threadIdx.x;
    const int w = tid >> 6, l = tid & 63;
    const int g = l >> 4, c = l & 15;
    const size_t hoff = (size_t)h * HD;
    ushort* sPh = &sP[w][0][0];
    ushort* sPl = &sP[w][1][0];

#define STAGE_KV(buf, kt_)                                                        \
  do {                                                                            \
    const int k0s = (kt_) * 64;                                                   \
    int cb0 = w * 64;                                                             \
    int ch0 = cb0 + l;                                                            \
    size_t kg0 = (size_t)(k0s + (ch0 & 63)) * D + hoff + (ch0 >> 6) * 8;          \
    size_t vg0 = (hoff + (ch0 & 63)) * (size_t)S + k0s + (ch0 >> 6) * 8;          \
    async_copy16(khp + kg0, &sK[buf][0][cb0 * 8]);                                \
    async_copy16(klp + kg0, &sK[buf][1][cb0 * 8]);                                \
    async_copy16(vth + vg0, &sV[buf][0][cb0 * 8]);                                \
    async_copy16(vtl + vg0, &sV[buf][1][cb0 * 8]);                                \
    int cb1 = 256 + w * 64;                                                       \
    int ch1 = cb1 + l;                                                            \
    size_t kg1 = (size_t)(k0s + (ch1 & 63)) * D + hoff + (ch1 >> 6) * 8;          \
    size_t vg1 = (hoff + (ch1 & 63)) * (size_t)S + k0s + (ch1 >> 6) * 8;          \
    async_copy16(khp + kg1, &sK[buf][0][cb1 * 8]);                                \
    async_copy16(klp + kg1, &sK[buf][1][cb1 * 8]);                                \
    async_copy16(vth + vg1, &sV[buf][0][cb1 * 8]);                                \
    async_copy16(vtl + vg1, &sV[buf][1][cb1 * 8]);                                \
  } while (0)

    // ---- Q fragments: A-layout direct from global (row = l&15, k = (l>>4)*8) ----
    const size_t qrow = (size_t)(qt * 64 + w * 16 + c) * D + hoff;
    bf16x8 aqh0 = *(const bf16x8*)(qhp + qrow + g * 8);
    bf16x8 aqh1 = *(const bf16x8*)(qhp + qrow + 32 + g * 8);
    bf16x8 aql0 = *(const bf16x8*)(qlp + qrow + g * 8);
    bf16x8 aql1 = *(const bf16x8*)(qlp + qrow + 32 + g * 8);

    STAGE_KV(0, 0);
    asm volatile("s_waitcnt vmcnt(0)" ::: "memory");
    __builtin_amdgcn_s_barrier();
    __builtin_amdgcn_sched_barrier(0);

    float m_[4], l_[4];
    f32x4 oacc[4];
#pragma unroll
    for (int r = 0; r < 4; r++) { m_[r] = -3e38f; l_[r] = 0.0f; }
#pragma unroll
    for (int fn = 0; fn < 4; fn++) oacc[fn] = (f32x4){0.f, 0.f, 0.f, 0.f};

    for (int kt = 0; kt <= qt; kt++) {
        const int cur = kt & 1;
        if (kt < qt) STAGE_KV(1 - cur, kt + 1);   // issue next tile early
        const ushort* sKh = &sK[cur][0][0];
        const ushort* sKl = &sK[cur][1][0];
        // ---- S = Q K^T (drop lo*lo) ----
        bf16x8 b0[4], b1[4], c0[4], c1[4];
#pragma unroll
        for (int fn = 0; fn < 4; fn++) {
            int u0 = (g * 64 + fn * 16 + c) * 8;
            int u1 = ((4 + g) * 64 + fn * 16 + c) * 8;
            b0[fn] = *(const bf16x8*)(sKh + u0);
            b1[fn] = *(const bf16x8*)(sKh + u1);
            c0[fn] = *(const bf16x8*)(sKl + u0);
            c1[fn] = *(const bf16x8*)(sKl + u1);
        }
        f32x4 sacc[4];
#pragma unroll
        for (int fn = 0; fn < 4; fn++) {
            f32x4 a = (f32x4){0.f, 0.f, 0.f, 0.f};
            a = __builtin_amdgcn_mfma_f32_16x16x32_bf16(aqh0, b0[fn], a, 0, 0, 0);
            a = __builtin_amdgcn_mfma_f32_16x16x32_bf16(aqh1, b1[fn], a, 0, 0, 0);
            a = __builtin_amdgcn_mfma_f32_16x16x32_bf16(aqh0, c0[fn], a, 0, 0, 0);
            a = __builtin_amdgcn_mfma_f32_16x16x32_bf16(aqh1, c1[fn], a, 0, 0, 0);
            a = __builtin_amdgcn_mfma_f32_16x16x32_bf16(aql0, b0[fn], a, 0, 0, 0);
            a = __builtin_amdgcn_mfma_f32_16x16x32_bf16(aql1, b1[fn], a, 0, 0, 0);
            sacc[fn] = a;
        }
        // ---- causal mask (diagonal tile only) ----
        if (kt == qt) {
#pragma unroll
            for (int fn = 0; fn < 4; fn++)
#pragma unroll
                for (int r = 0; r < 4; r++)
                    if (fn * 16 + c > w * 16 + g * 4 + r) sacc[fn][r] = -3e38f;
        }
        // ---- online softmax in exp2 domain ----
        float alpha[4];
#pragma unroll
        for (int r = 0; r < 4; r++) {
            float rm = fmaxf(fmaxf(sacc[0][r], sacc[1][r]), fmaxf(sacc[2][r], sacc[3][r]));
#pragma unroll
            for (int off = 1; off < 16; off <<= 1) rm = fmaxf(rm, __shfl_xor(rm, off));
            float mn = fmaxf(m_[r], rm);
            alpha[r] = exp2f(m_[r] - mn);
            m_[r] = mn;
            float rs = 0.0f;
#pragma unroll
            for (int fn = 0; fn < 4; fn++) {
                float pp = exp2f(sacc[fn][r] - mn);
                sacc[fn][r] = pp;
                rs += pp;
            }
#pragma unroll
            for (int off = 1; off < 16; off <<= 1) rs += __shfl_xor(rs, off);
            l_[r] = l_[r] * alpha[r] + rs;
        }
#pragma unroll
        for (int fn = 0; fn < 4; fn++)
#pragma unroll
            for (int r = 0; r < 4; r++) oacc[fn][r] *= alpha[r];
        // ---- P (C-layout) -> per-wave LDS (A-layout), hi/lo bf16 ----
#pragma unroll
        for (int fn = 0; fn < 4; fn++) {
            int chunk = fn * 2 + (c >> 3);
#pragma unroll
            for (int r = 0; r < 4; r++) {
                float pp = sacc[fn][r];
                ushort ph = f2bf(pp);
                int off = (chunk * 16 + g * 4 + r) * 8 + (c & 7);
                sPh[off] = ph;
                sPl[off] = f2bf(pp - bf2f(ph));
            }
        }
        // ---- O += P V (drop lo*lo) ----
        const ushort* sVh = &sV[cur][0][0];
        const ushort* sVl = &sV[cur][1][0];
        bf16x8 pa0 = *(const bf16x8*)(sPh + (g * 16 + c) * 8);
        bf16x8 pa1 = *(const bf16x8*)(sPh + ((4 + g) * 16 + c) * 8);
        bf16x8 pb0 = *(const bf16x8*)(sPl + (g * 16 + c) * 8);
        bf16x8 pb1 = *(const bf16x8*)(sPl + ((4 + g) * 16 + c) * 8);
#pragma unroll
        for (int fn = 0; fn < 4; fn++) {
            int u0 = (g * 64 + fn * 16 + c) * 8;
            int u1 = ((4 + g) * 64 + fn * 16 + c) * 8;
            bf16x8 vh0 = *(const bf16x8*)(sVh + u0);
            bf16x8 vh1 = *(const bf16x8*)(sVh + u1);
            bf16x8 vl0 = *(const bf16x8*)(sVl + u0);
            bf16x8 vl1 = *(const bf16x8*)(sVl + u1);
            f32x4 o = oacc[fn];
            o = __builtin_amdgcn_mfma_f32_16x16x32_bf16(pa0, vh0, o, 0, 0, 0);
            o = __builtin_amdgcn_mfma_f32_16x16x32_bf16(pa1, vh1, o, 0, 0, 0);
            o = __builtin_amdgcn_mfma_f32_16x16x32_bf16(pa0, vl0, o, 0, 0, 0);
            o = __builtin_amdgcn_mfma_f32_16x16x32_bf16(pa1, vl1, o, 0, 0, 0);
            o = __builtin_amdgcn_mfma_f32_16x16x32_bf16(pb0, vh0, o, 0, 0, 0);
            o = __builtin_amdgcn_mfma_f32_16x16x32_bf16(pb1, vh1, o, 0, 0, 0);
            oacc[fn] = o;
        }
        if (kt < qt) {
            asm volatile("s_waitcnt vmcnt(0)" ::: "memory");  // next tile staged
            __builtin_amdgcn_s_barrier();
            __builtin_amdgcn_sched_barrier(0);
        }
    }
    // ---- epilogue: normalize + store bf16x2 planes ----
#pragma unroll
    for (int r = 0; r < 4; r++) {
        float inv = 1.0f / l_[r];
        size_t orow = (size_t)(qt * 64 + w * 16 + g * 4 + r) * D + hoff;
#pragma unroll
        for (int fn = 0; fn < 4; fn++) {
            float v = oacc[fn][r] * inv;
            ushort hi = f2bf(v);
            oh_out[orow + fn * 16 + c] = hi;
            ol_out[orow + fn * 16 + c] = f2bf(v - bf2f(hi));
        }
    }
#undef STAGE_KV
}

// ============ Router (fp32 — routing must match reference exactly) ============
__global__ __launch_bounds__(64) void router_kernel(const float* __restrict__ x,
    const float* __restrict__ wr, int* __restrict__ ei, float* __restrict__ ew,
    int* __restrict__ counts, float* __restrict__ prob_sums, float* __restrict__ z_sum)
{
    int t = blockIdx.x, lane = threadIdx.x;
    const float* xr = x + (size_t)t * D;
    float p[E] = {};
    for (int d = lane; d < D; d += 64) {
        float xd = xr[d];
        const float* wrow = wr + d * E;
#pragma unroll
        for (int e = 0; e < E; e++) p[e] = fmaf(xd, wrow[e], p[e]);
    }
#pragma unroll
    for (int off = 32; off > 0; off >>= 1) {
#pragma unroll
        for (int e = 0; e < E; e++) p[e] += __shfl_xor(p[e], off);
    }
    float m = p[0];
#pragma unroll
    for (int e = 1; e < E; e++) m = fmaxf(m, p[e]);
    float sum = 0.0f, pr[E];
#pragma unroll
    for (int e = 0; e < E; e++) { pr[e] = expf(p[e] - m); sum += pr[e]; }
    float invs = 1.0f / sum;
#pragma unroll
    for (int e = 0; e < E; e++) pr[e] *= invs;
    float lse = m + logf(sum);
    int e1 = 0; float b1 = pr[0];
#pragma unroll
    for (int e = 1; e < E; e++) if (pr[e] > b1) { b1 = pr[e]; e1 = e; }
    int e2 = -1; float b2 = -1.0f;
#pragma unroll
    for (int e = 0; e < E; e++) if (e != e1 && pr[e] > b2) { b2 = pr[e]; e2 = e; }
    float wsum = b1 + b2;
    if (lane == 0) {
        ei[2 * t] = e1; ei[2 * t + 1] = e2;
        ew[2 * t] = b1 / wsum; ew[2 * t + 1] = b2 / wsum;
        atomicAdd(&counts[e1], 1);
        atomicAdd(&counts[e2], 1);
        atomicAdd(z_sum, lse * lse);
    }
    if (lane < E) atomicAdd(&prob_sums[lane], pr[lane]);
}

__global__ void zero_kernel(int* counts, float* prob_sums, float* z_sum)
{
    int tid = threadIdx.x;
    if (tid < E) { counts[tid] = 0; prob_sums[tid] = 0.0f; }
    if (tid == 0) *z_sum = 0.0f;
}

__global__ void finalize_kernel(const int* __restrict__ counts, const float* __restrict__ prob_sums,
    const float* __restrict__ z_sum, int* __restrict__ offs, int* __restrict__ cursor,
    float* __restrict__ aux_out)
{
    if (threadIdx.x == 0) {
        int off = 0;
        for (int e = 0; e < E; e++) { offs[e] = off; cursor[e] = off; off += counts[e]; }
        float z = 1e-3f * (*z_sum) * (1.0f / S);
        float lb = 0.0f;
        for (int e = 0; e < E; e++) lb += ((float)counts[e] / (float)S) * (prob_sums[e] / (float)S);
        lb *= 1e-2f;
        *aux_out = z + lb;
    }
}

__global__ __launch_bounds__(256) void scatter_kernel(const int* __restrict__ ei,
    int* __restrict__ cursor, int* __restrict__ tlist, int* __restrict__ slot_of)
{
    int t = blockIdx.x * 256 + threadIdx.x;
    if (t >= S) return;
#pragma unroll
    for (int kk = 0; kk < 2; kk++) {
        int e = ei[2 * t + kk];
        int slot = atomicAdd(&cursor[e], 1);
        tlist[slot] = t;
        slot_of[2 * t + kk] = slot;
    }
}

__global__ __launch_bounds__(256) void gather_kernel(const ushort* __restrict__ xbf,
    const int* __restrict__ tlist, ushort* __restrict__ xg)
{
    int slot = blockIdx.x;
    int t4 = threadIdx.x * 4;
    ushort4 vv;
    if (slot < NSLOTS) {
        int tok = tlist[slot];
        vv = *(const ushort4*)(xbf + (size_t)tok * D + t4);
    } else {
        vv = make_ushort4(0, 0, 0, 0);
    }
    *(ushort4*)(xg + (size_t)slot * D + t4) = vv;
}

// ============ MoE gate+up GEMM, N-concat over [gate|up], 64x128 tile, BK=32, depth-2 ============
// Grid: (2F/128=32, NSLOTS/64=64, E). 36 KB LDS -> 4 blocks/CU.
__global__ __launch_bounds__(256) void moe_gateup_mfma(const ushort* __restrict__ xg,
    const ushort* __restrict__ wgt, const ushort* __restrict__ wut,
    ushort* __restrict__ Hg, ushort* __restrict__ Hu,
    const int* __restrict__ offs, const int* __restrict__ cnts)
{
    const int e = blockIdx.z;
    const int cnt = cnts[e];
    const int m0 = blockIdx.y * 64;
    if (m0 >= cnt) return;
    const int off = offs[e];
    const int n0g = blockIdx.x * 128;   // over concat 2F
    const bool isg = n0g < F;
    const ushort* Wt = isg ? (wgt + (size_t)e * F * D + (size_t)n0g * D)
                           : (wut + (size_t)e * F * D + (size_t)(n0g - F) * D);
    ushort* Outp = isg ? Hg : Hu;
    const int ncol0 = isg ? n0g : n0g - F;
    __shared__ ushort As[3][2048], Ws[3][4096];
    const int tid = threadIdx.x;
    const int w = tid >> 6, l = tid & 63;
    const int wm = (w >> 1) * 32, wn = (w & 1) * 64;
    const int kc = l >> 4, lr = l & 15;
    const ushort* Arow = xg + (size_t)(off + m0) * D;

#define STAGE_GU(buf, t_)                                                     \
  do {                                                                        \
    int kbase = (t_) * 32;                                                    \
    {                                                                         \
      int ckc = tid >> 6, r = tid & 63;                                       \
      int loff = (w * 64) * 8;                                                \
      async_copy16(Arow + (size_t)r * D + kbase + ckc * 8, As[buf] + loff);   \
    }                                                                         \
    _Pragma("unroll")                                                         \
    for (int it = 0; it < 2; it++) {                                          \
      int cch = it * 256 + tid;                                               \
      int ckc = cch >> 7, r = cch & 127;                                      \
      int loff = (it * 256 + w * 64) * 8;                                     \
      async_copy16(Wt + (size_t)r * D + kbase + ckc * 8, Ws[buf] + loff);     \
    }                                                                         \
  } while (0)

    f32x4 acc[2][4];
#pragma unroll
    for (int i = 0; i < 2; i++)
#pragma unroll
        for (int j = 0; j < 4; j++) acc[i][j] = (f32x4){0.f, 0.f, 0.f, 0.f};

    const int NT = D / 32;   // 32
    STAGE_GU(0, 0);
    STAGE_GU(1, 1);
    for (int t = 0; t < NT; ++t) {
        const int cur = t % 3;
        if (t + 1 < NT) { asm volatile("s_waitcnt vmcnt(3)" ::: "memory"); }
        else            { asm volatile("s_waitcnt vmcnt(0)" ::: "memory"); }
        __builtin_amdgcn_s_barrier();
        __builtin_amdgcn_sched_barrier(0);
        if (t + 2 < NT) STAGE_GU((t + 2) % 3, t + 2);
        bf16x8 af[2], wf[4];
#pragma unroll
        for (int f = 0; f < 2; f++)
            af[f] = *(const bf16x8*)(As[cur] + (kc * 64 + wm + f * 16 + lr) * 8);
#pragma unroll
        for (int f = 0; f < 4; f++)
            wf[f] = *(const bf16x8*)(Ws[cur] + (kc * 128 + wn + f * 16 + lr) * 8);
#pragma unroll
        for (int fm = 0; fm < 2; fm++)
#pragma unroll
            for (int fn = 0; fn < 4; fn++)
                acc[fm][fn] = __builtin_amdgcn_mfma_f32_16x16x32_bf16(af[fm], wf[fn], acc[fm][fn], 0, 0, 0);
    }
#undef STAGE_GU
#pragma unroll
    for (int fm = 0; fm < 2; fm++)
#pragma unroll
        for (int fn = 0; fn < 4; fn++)
#pragma unroll
            for (int r = 0; r < 4; r++) {
                int rloc = m0 + wm + fm * 16 + (l >> 4) * 4 + r;
                if (rloc < cnt) {
                    int col = ncol0 + wn + fn * 16 + (l & 15);
                    Outp[(size_t)(off + rloc) * F + col] = f2bf(acc[fm][fn][r]);
                }
            }
}

// ============ SiLU(g)*u elementwise ============
__global__ __launch_bounds__(256) void silu_kernel(const ushort* __restrict__ Gout,
    const ushort* __restrict__ Uout, ushort* __restrict__ Hb)
{
    int slot = blockIdx.x;
    int f0 = threadIdx.x * 8;
    bf16x8 gv = *(const bf16x8*)(Gout + (size_t)slot * F + f0);
    bf16x8 uv = *(const bf16x8*)(Uout + (size_t)slot * F + f0);
    bf16x8 o;
#pragma unroll
    for (int j = 0; j < 8; j++) {
        float g = bf2f((ushort)gv[j]);
        float u = bf2f((ushort)uv[j]);
        o[j] = (short)f2bf(g / (1.0f + expf(-g)) * u);
    }
    *(bf16x8*)(Hb + (size_t)slot * F + f0) = o;
}

// ============ MoE down GEMM (64x128 tile, BK=32, depth-2 pipeline) ============
// Grid: (D/128=8, NSLOTS/64=64, E) -> ~512 active blocks; 36 KB LDS -> 4/CU.
__global__ __launch_bounds__(256) void moe_down_mfma(const ushort* __restrict__ Hb,
    const ushort* __restrict__ wdt, ushort* __restrict__ yb,
    const int* __restrict__ offs, const int* __restrict__ cnts)
{
    const int e = blockIdx.z;
    const int cnt = cnts[e];
    const int m0 = blockIdx.y * 64;
    if (m0 >= cnt) return;
    const int off = offs[e];
    const ushort* Bt = wdt + (size_t)e * D * F;
    const int n0 = blockIdx.x * 128;
    __shared__ ushort As[3][2048], Bs[3][4096];
    const int tid = threadIdx.x;
    const int w = tid >> 6, l = tid & 63;
    const int wm = (w >> 1) * 32, wn = (w & 1) * 64;
    const int kc = l >> 4, lr = l & 15;
    const ushort* Arow = Hb + (size_t)(off + m0) * F;
    const ushort* Brow = Bt + (size_t)n0 * F;

#define STAGE_DN(buf, t_)                                                     \
  do {                                                                        \
    int kbase = (t_) * 32;                                                    \
    {                                                                         \
      int ckc = tid >> 6, r = tid & 63;                                       \
      int loff = (w * 64) * 8;                                                \
      async_copy16(Arow + (size_t)r * F + kbase + ckc * 8, As[buf] + loff);   \
    }                                                                         \
    _Pragma("unroll")                                                         \
    for (int it = 0; it < 2; it++) {                                          \
      int cch = it * 256 + tid;                                               \
      int ckc = cch >> 7, r = cch & 127;                                      \
      int loff = (it * 256 + w * 64) * 8;                                     \
      async_copy16(Brow + (size_t)r * F + kbase + ckc * 8, Bs[buf] + loff);   \
    }                                                                         \
  } while (0)

    f32x4 acc[2][4];
#pragma unroll
    for (int i = 0; i < 2; i++)
#pragma unroll
        for (int j = 0; j < 4; j++) acc[i][j] = (f32x4){0.f,0.f,0.f,0.f};

    const int NT = F / 32;   // 64
    STAGE_DN(0, 0);
    STAGE_DN(1, 1);
    for (int t = 0; t < NT; ++t) {
        const int cur = t % 3;
        if (t + 1 < NT) { asm volatile("s_waitcnt vmcnt(3)" ::: "memory"); }
        else            { asm volatile("s_waitcnt vmcnt(0)" ::: "memory"); }
        __builtin_amdgcn_s_barrier();
        __builtin_amdgcn_sched_barrier(0);
        if (t + 2 < NT) STAGE_DN((t + 2) % 3, t + 2);
        bf16x8 af[2], bfr[4];
#pragma unroll
        for (int f = 0; f < 2; f++)
            af[f] = *(const bf16x8*)(As[cur] + (kc * 64 + wm + f * 16 + lr) * 8);
#pragma unroll
        for (int f = 0; f < 4; f++)
            bfr[f] = *(const bf16x8*)(Bs[cur] + (kc * 128 + wn + f * 16 + lr) * 8);
#pragma unroll
        for (int fm = 0; fm < 2; fm++)
#pragma unroll
            for (int fn = 0; fn < 4; fn++)
                acc[fm][fn] = __builtin_amdgcn_mfma_f32_16x16x32_bf16(af[fm], bfr[fn], acc[fm][fn], 0, 0, 0);
    }
#undef STAGE_DN
#pragma unroll
    for (int fm = 0; fm < 2; fm++)
#pragma unroll
        for (int fn = 0; fn < 4; fn++)
#pragma unroll
            for (int r = 0; r < 4; r++) {
                int rloc = m0 + wm + fm * 16 + (l >> 4) * 4 + r;
                if (rloc < cnt) {
                    int col = n0 + wn + fn * 16 + (l & 15);
                    yb[(size_t)(off + rloc) * D + col] = f2bf(acc[fm][fn][r]);
                }
            }
}

// ============ Combine ============
__global__ __launch_bounds__(256) void combine_kernel(const float* __restrict__ hs2,
    const ushort* __restrict__ yb, const float* __restrict__ ew,
    const int* __restrict__ slot_of, float* __restrict__ out)
{
    int t = blockIdx.x, tid = threadIdx.x;
    int s0 = slot_of[2 * t], s1 = slot_of[2 * t + 1];
    float w0 = ew[2 * t], w1 = ew[2 * t + 1];
    float4 a = *(const float4*)(hs2 + (size_t)t * D + tid * 4);
    ushort4 y0 = *(const ushort4*)(yb + (size_t)s0 * D + tid * 4);
    ushort4 y1 = *(const ushort4*)(yb + (size_t)s1 * D + tid * 4);
    float4 o;
    o.x = a.x + w0 * bf2f(y0.x) + w1 * bf2f(y1.x);
    o.y = a.y + w0 * bf2f(y0.y) + w1 * bf2f(y1.y);
    o.z = a.z + w0 * bf2f(y0.z) + w1 * bf2f(y1.z);
    o.w = a.w + w0 * bf2f(y0.w) + w1 * bf2f(y1.w);
    *(float4*)(out + (size_t)t * D + tid * 4) = o;
}

// ============ launch ============
extern "C" void kernel_launch(void* const* d_in, const int* in_sizes, int n_in,
                              void* d_out, int out_size, void* d_ws, size_t ws_size,
                              hipStream_t stream)
{
    (void)in_sizes; (void)n_in; (void)out_size; (void)ws_size;
    const float* hs   = (const float*)d_in[0];
    const float* ln1w = (const float*)d_in[3];
    const float* ln1b = (const float*)d_in[4];
    const float* ln2w = (const float*)d_in[5];
    const float* ln2b = (const float*)d_in[6];
    const float* wq   = (const float*)d_in[7];
    const float* wk   = (const float*)d_in[8];
    const float* wv   = (const float*)d_in[9];
    const float* wo   = (const float*)d_in[10];
    const float* wr   = (const float*)d_in[11];
    const float* wg   = (const float*)d_in[12];
    const float* wu   = (const float*)d_in[13];
    const float* wd   = (const float*)d_in[14];
    float* out = (float*)d_out;

    const size_t TD = (size_t)S * D;
    char* p = (char*)d_ws;
    auto alloc = [&](size_t bytes) { char* r = p; p += (bytes + 255) & ~(size_t)255; return r; };

    ushort* wgt  = (ushort*)alloc((size_t)E * D * F * 2);
    ushort* wut  = (ushort*)alloc((size_t)E * D * F * 2);
    ushort* wdt  = (ushort*)alloc((size_t)E * D * F * 2);
    ushort* wqh  = (ushort*)alloc((size_t)D * D * 2);
    ushort* wqlo = (ushort*)alloc((size_t)D * D * 2);
    ushort* wkh  = (ushort*)alloc((size_t)D * D * 2);
    ushort* wklo = (ushort*)alloc((size_t)D * D * 2);
    ushort* wvh  = (ushort*)alloc((size_t)D * D * 2);
    ushort* wvlo = (ushort*)alloc((size_t)D * D * 2);
    ushort* woh  = (ushort*)alloc((size_t)D * D * 2);
    ushort* wolo = (ushort*)alloc((size_t)D * D * 2);
    ushort* xh   = (ushort*)alloc(TD * 2);
    ushort* xl   = (ushort*)alloc(TD * 2);
    float*  qb   = (float*)alloc(TD * 4);   // fp32 Q; later: Gout = qb..kb (16.78 MB)
    float*  kb   = (float*)alloc(TD * 4);
    float*  vb   = (float*)alloc(TD * 4);   // fp32 V; later: Uout = vb..atl (16.78 MB)
    ushort* ath  = (ushort*)alloc(TD * 2);
    ushort* atl  = (ushort*)alloc(TD * 2);
    float*  hs2  = (float*)alloc(TD * 4);
    float*  xf32 = (float*)alloc(TD * 4);
    ushort* xbf  = (ushort*)alloc(TD * 2);
    ushort* xg   = (ushort*)alloc((size_t)NPAD * D * 2);
    ushort* Hb   = (ushort*)alloc((size_t)NPAD * F * 2);
    ushort* yb   = (ushort*)alloc((size_t)NPAD * D * 2);
    ushort* khp  = (ushort*)alloc(TD * 2);   // K bf16 hi (post-rope), row-major [S][D]
    ushort* klp  = (ushort*)alloc(TD * 2);   // K bf16 lo
    ushort* vth  = (ushort*)alloc(TD * 2);   // V^T bf16 hi, [D][S]
    ushort* vtl  = (ushort*)alloc(TD * 2);   // V^T bf16 lo
    float*  ewb       = (float*)alloc(2 * S * 4);
    float*  prob_sums = (float*)alloc(8 * 4);
    float*  z_sum     = (float*)alloc(8 * 4);
    int* ei      = (int*)alloc(2 * S * 4);
    int* slot_of = (int*)alloc(2 * S * 4);
    int* tlist   = (int*)alloc(NSLOTS * 4);
    int* counts  = (int*)alloc(8 * 4);
    int* offs    = (int*)alloc(8 * 4);
    int* cursor  = (int*)alloc(8 * 4);

    // Raw gate/up GEMM outputs alias dead attention fp32 buffers (exact-size fit):
    ushort* Gout = (ushort*)qb;
    ushort* Uout = (ushort*)vb;

    // ---- weight prep ----
    castT2_kernel<<<dim3(D / 64, D / 64, 1), 256, 0, stream>>>(wq, wqh, wqlo, D, D);
    castT2_kernel<<<dim3(D / 64, D / 64, 1), 256, 0, stream>>>(wk, wkh, wklo, D, D);
    castT2_kernel<<<dim3(D / 64, D / 64, 1), 256, 0, stream>>>(wv, wvh, wvlo, D, D);
    castT2_kernel<<<dim3(D / 64, D / 64, 1), 256, 0, stream>>>(wo, woh, wolo, D, D);
    castT_kernel<<<dim3(F / 64, D / 64, E), 256, 0, stream>>>(wg, wgt, D, F);
    castT_kernel<<<dim3(F / 64, D / 64, E), 256, 0, stream>>>(wu, wut, D, F);
    castT_kernel<<<dim3(D / 64, F / 64, E), 256, 0, stream>>>(wd, wdt, F, D);

    // ---- attention sub-block ----
    ln_kernel<<<S, 256, 0, stream>>>(hs, ln1w, ln1b, nullptr, xh, xl);
    qkv_mfma2<<<dim3(D / 128, S / 64, 3), 256, 0, stream>>>(xh, xl, wqh, wqlo, wkh, wklo, wvh, wvlo, qb, kb, vb);
    rope_cast<<<S, 512, 0, stream>>>(qb, kb, xh, xl, khp, klp);
    castT2_kernel<<<dim3(D / 64, S / 64, 1), 256, 0, stream>>>(vb, vth, vtl, S, D);
    attn_mfma<<<dim3(32, 16), 256, 0, stream>>>(xh, xl, khp, klp, vth, vtl, ath, atl);
    wo_mfma2<<<dim3(D / 128, S / 64), 256, 0, stream>>>(ath, atl, woh, wolo, hs, hs2);

    // ---- MoE sub-block ----
    ln_kernel<<<S, 256, 0, stream>>>(hs2, ln2w, ln2b, xf32, xbf, nullptr);
    zero_kernel<<<1, 64, 0, stream>>>(counts, prob_sums, z_sum);
    router_kernel<<<S, 64, 0, stream>>>(xf32, wr, ei, ewb, counts, prob_sums, z_sum);
    finalize_kernel<<<1, 64, 0, stream>>>(counts, prob_sums, z_sum, offs, cursor, out + TD);
    scatter_kernel<<<S / 256, 256, 0, stream>>>(ei, cursor, tlist, slot_of);
    gather_kernel<<<NPAD, 256, 0, stream>>>(xbf, tlist, xg);
    moe_gateup_mfma<<<dim3(2 * F / 128, NSLOTS / 64, E), 256, 0, stream>>>(xg, wgt, wut, Gout, Uout, offs, counts);
    silu_kernel<<<NSLOTS, 256, 0, stream>>>(Gout, Uout, Hb);
    moe_down_mfma<<<dim3(D / 128, NSLOTS / 64, E), 256, 0, stream>>>(Hb, wdt, yb, offs, counts);
    combine_kernel<<<S, 256, 0, stream>>>(hs2, yb, ewb, slot_of, out);
}

// Round 6
// 748.803 us; speedup vs baseline: 1.1603x; 1.1513x over previous
//
#include <hip/hip_runtime.h>
#include <math.h>

static constexpr int S = 2048;          // tokens (B=1)
static constexpr int D = 1024;          // model dim
static constexpr int H = 16;            // heads
static constexpr int HD = 64;           // head dim
static constexpr int E = 8;             // experts
static constexpr int F = 2048;          // ffn dim
static constexpr int NSLOTS = S * 2;    // 4096
static constexpr int NPAD = NSLOTS + 128;

typedef __attribute__((ext_vector_type(8))) short bf16x8;
typedef __attribute__((ext_vector_type(4))) float f32x4;

__device__ __forceinline__ float bf2f(ushort u) {
    uint32_t x = ((uint32_t)u) << 16; float f; __builtin_memcpy(&f, &x, 4); return f;
}
__device__ __forceinline__ ushort f2bf(float f) {
    uint32_t x; __builtin_memcpy(&x, &f, 4);
    return (ushort)((x + 0x7fffu + ((x >> 16) & 1u)) >> 16);
}
__device__ __forceinline__ void async_copy16(const void* gptr, void* ldsptr) {
    __builtin_amdgcn_global_load_lds(
        (const __attribute__((address_space(1))) void*)gptr,
        (__attribute__((address_space(3))) void*)ldsptr, 16, 0, 0);
}

// ============ fp32 [K][N] -> bf16 TILED: per (p=n/128, t=k/32) 512 chunks of 8;
// chunk c=(kc*128+n): src[(t*32+kc*8+j)][p*128+n]. Matches GEMM LDS image exactly. ============
__global__ __launch_bounds__(256) void castTileW_kernel(const float* __restrict__ src,
    ushort* __restrict__ dst, int K, int N)
{
    __shared__ float T[32][132];
    src += (size_t)blockIdx.z * K * N;
    dst += (size_t)blockIdx.z * K * N;
    const int p = blockIdx.x, t = blockIdx.y;
    const int tid = threadIdx.x;
    const int k = tid >> 3, nb = (tid & 7) * 16;
    const float* sr = src + (size_t)(t * 32 + k) * N + p * 128 + nb;
#pragma unroll
    for (int q = 0; q < 4; q++) {
        float4 v = *(const float4*)(sr + q * 4);
        T[k][nb + q * 4 + 0] = v.x; T[k][nb + q * 4 + 1] = v.y;
        T[k][nb + q * 4 + 2] = v.z; T[k][nb + q * 4 + 3] = v.w;
    }
    __syncthreads();
    ushort* dbase = dst + ((size_t)p * (K / 32) + t) * 4096;
#pragma unroll
    for (int q = 0; q < 2; q++) {
        int c = tid * 2 + q;
        int kc = c >> 7, n = c & 127;
        bf16x8 o;
#pragma unroll
        for (int j = 0; j < 8; j++) o[j] = (short)f2bf(T[kc * 8 + j][n]);
        *(bf16x8*)(dbase + (size_t)c * 8) = o;
    }
}

// ============ fp32 [K][N] -> bf16x2 hi/lo TILED planes (same chunk layout) ============
__global__ __launch_bounds__(256) void castTile2W_kernel(const float* __restrict__ src,
    ushort* __restrict__ dh, ushort* __restrict__ dl, int K, int N)
{
    __shared__ float T[32][132];
    const int p = blockIdx.x, t = blockIdx.y;
    const int tid = threadIdx.x;
    const int k = tid >> 3, nb = (tid & 7) * 16;
    const float* sr = src + (size_t)(t * 32 + k) * N + p * 128 + nb;
#pragma unroll
    for (int q = 0; q < 4; q++) {
        float4 v = *(const float4*)(sr + q * 4);
        T[k][nb + q * 4 + 0] = v.x; T[k][nb + q * 4 + 1] = v.y;
        T[k][nb + q * 4 + 2] = v.z; T[k][nb + q * 4 + 3] = v.w;
    }
    __syncthreads();
    size_t tb = ((size_t)p * (K / 32) + t) * 4096;
#pragma unroll
    for (int q = 0; q < 2; q++) {
        int c = tid * 2 + q;
        int kc = c >> 7, n = c & 127;
        bf16x8 oh, ol;
#pragma unroll
        for (int j = 0; j < 8; j++) {
            float v = T[kc * 8 + j][n];
            ushort h = f2bf(v);
            oh[j] = (short)h;
            ol[j] = (short)f2bf(v - bf2f(h));
        }
        *(bf16x8*)(dh + tb + (size_t)c * 8) = oh;
        *(bf16x8*)(dl + tb + (size_t)c * 8) = ol;
    }
}

// ============ cast + transpose fp32 [K][N] -> bf16x2 hi/lo planes [N][K] (attn V^T) ============
__global__ __launch_bounds__(256) void castT2_kernel(const float* __restrict__ src,
    ushort* __restrict__ dh, ushort* __restrict__ dl, int K, int N)
{
    __shared__ float T[64][65];
    int k0 = blockIdx.y * 64, n0 = blockIdx.x * 64;
    int t = threadIdx.x;
    int r = t >> 4, c4 = (t & 15) * 4;
#pragma unroll
    for (int it = 0; it < 4; it++) {
        float4 v = *(const float4*)(src + (size_t)(k0 + r + it * 16) * N + n0 + c4);
        T[r + it * 16][c4 + 0] = v.x; T[r + it * 16][c4 + 1] = v.y;
        T[r + it * 16][c4 + 2] = v.z; T[r + it * 16][c4 + 3] = v.w;
    }
    __syncthreads();
#pragma unroll
    for (int it = 0; it < 4; it++) {
        int rr = r + it * 16;
        ushort4 oh, ol;
        float v0 = T[c4 + 0][rr], v1 = T[c4 + 1][rr], v2 = T[c4 + 2][rr], v3 = T[c4 + 3][rr];
        oh.x = f2bf(v0); ol.x = f2bf(v0 - bf2f(oh.x));
        oh.y = f2bf(v1); ol.y = f2bf(v1 - bf2f(oh.y));
        oh.z = f2bf(v2); ol.z = f2bf(v2 - bf2f(oh.z));
        oh.w = f2bf(v3); ol.w = f2bf(v3 - bf2f(oh.w));
        *(ushort4*)(dh + (size_t)(n0 + rr) * K + k0 + c4) = oh;
        *(ushort4*)(dl + (size_t)(n0 + rr) * K + k0 + c4) = ol;
    }
}

// ============ LayerNorm: optional row-fp32 / row-bf16 / TILED hi+lo outputs ============
__global__ __launch_bounds__(256) void ln_kernel(const float* __restrict__ x,
    const float* __restrict__ w, const float* __restrict__ b,
    float* __restrict__ yf, ushort* __restrict__ yh,
    ushort* __restrict__ th, ushort* __restrict__ tl)
{
    int tk = blockIdx.x, tid = threadIdx.x;
    __shared__ float redx[256];
    __shared__ float redy[256];
    const float* xr = x + (size_t)tk * D;
    float4 xv = *(const float4*)(xr + tid * 4);
    redx[tid] = xv.x + xv.y + xv.z + xv.w;
    redy[tid] = xv.x * xv.x + xv.y * xv.y + xv.z * xv.z + xv.w * xv.w;
    __syncthreads();
    for (int st = 128; st > 0; st >>= 1) {
        if (tid < st) { redx[tid] += redx[tid + st]; redy[tid] += redy[tid + st]; }
        __syncthreads();
    }
    float mean = redx[0] * (1.0f / D);
    float var  = redy[0] * (1.0f / D) - mean * mean;
    float rstd = rsqrtf(var + 1e-5f);
    float4 wv = *(const float4*)(w + tid * 4);
    float4 bv = *(const float4*)(b + tid * 4);
    float4 o;
    o.x = (xv.x - mean) * rstd * wv.x + bv.x;
    o.y = (xv.y - mean) * rstd * wv.y + bv.y;
    o.z = (xv.z - mean) * rstd * wv.z + bv.z;
    o.w = (xv.w - mean) * rstd * wv.w + bv.w;
    if (yf) *(float4*)(yf + (size_t)tk * D + tid * 4) = o;
    ushort4 oh;
    oh.x = f2bf(o.x); oh.y = f2bf(o.y); oh.z = f2bf(o.z); oh.w = f2bf(o.w);
    if (yh) *(ushort4*)(yh + (size_t)tk * D + tid * 4) = oh;
    if (th) {
        int d0 = tid * 4;
        size_t ta = (((size_t)(tk >> 6) * 32 + (d0 >> 5)) * 256
                     + (size_t)((d0 >> 3) & 3) * 64 + (tk & 63)) * 8 + (d0 & 7);
        *(ushort4*)(th + ta) = oh;
        ushort4 ol;
        ol.x = f2bf(o.x - bf2f(oh.x)); ol.y = f2bf(o.y - bf2f(oh.y));
        ol.z = f2bf(o.z - bf2f(oh.z)); ol.w = f2bf(o.w - bf2f(oh.w));
        *(ushort4*)(tl + ta) = ol;
    }
}

// ============ RoPE + bf16 hi/lo cast (row-major Q/K planes for attention) ============
__global__ __launch_bounds__(512) void rope_cast(const float* __restrict__ q,
    const float* __restrict__ k, ushort* __restrict__ qh, ushort* __restrict__ ql,
    ushort* __restrict__ kh, ushort* __restrict__ kl)
{
    int t = blockIdx.x;
    int idx = threadIdx.x;
    int hh = idx >> 5, i = idx & 31;
    float invf = powf(10000.0f, -(float)i / 32.0f);
    float ang = (float)t * invf;
    float cc = cosf(ang), ss = sinf(ang);
    size_t base = (size_t)t * D + hh * HD + i;
    const float QS = 0.125f * 1.4426950408889634f;
    float q1 = q[base], q2 = q[base + 32];
    float qr1 = (q1 * cc - q2 * ss) * QS;
    float qr2 = (q2 * cc + q1 * ss) * QS;
    ushort h1 = f2bf(qr1); qh[base] = h1;      ql[base] = f2bf(qr1 - bf2f(h1));
    ushort h2 = f2bf(qr2); qh[base + 32] = h2; ql[base + 32] = f2bf(qr2 - bf2f(h2));
    float k1 = k[base], k2 = k[base + 32];
    float kr1 = k1 * cc - k2 * ss;
    float kr2 = k2 * cc + k1 * ss;
    ushort h3 = f2bf(kr1); kh[base] = h3;      kl[base] = f2bf(kr1 - bf2f(h3));
    ushort h4 = f2bf(kr2); kh[base + 32] = h4; kl[base + 32] = f2bf(kr2 - bf2f(h4));
}

// ============ bf16x2 MFMA k-loop, TILED operands: 64x128 tile, BK=32, depth-1 ============
// All staging loads are contiguous (global order == LDS linear order).
__device__ __forceinline__ void stage_t2(const ushort* __restrict__ Ath, const ushort* __restrict__ Atl,
    const ushort* __restrict__ Bth, const ushort* __restrict__ Btl, size_t abase, size_t bbase,
    ushort* sAh, ushort* sAl, ushort* sBh, ushort* sBl, int tid, int w)
{
    const int wo8 = w * 512;     // w*64 chunks * 8
    async_copy16(Ath + abase + (size_t)tid * 8, sAh + wo8);
    async_copy16(Atl + abase + (size_t)tid * 8, sAl + wo8);
    async_copy16(Bth + bbase + (size_t)tid * 8, sBh + wo8);
    async_copy16(Btl + bbase + (size_t)tid * 8, sBl + wo8);
    async_copy16(Bth + bbase + (size_t)(256 + tid) * 8, sBh + 2048 + wo8);
    async_copy16(Btl + bbase + (size_t)(256 + tid) * 8, sBl + 2048 + wo8);
}

__device__ __forceinline__ void mfma2_kloop_t(const ushort* __restrict__ Ath,
    const ushort* __restrict__ Atl, const ushort* __restrict__ Bth, const ushort* __restrict__ Btl,
    int KT, int mt,
    ushort (&sAh)[2][2048], ushort (&sAl)[2][2048],
    ushort (&sBh)[2][4096], ushort (&sBl)[2][4096], f32x4 (&acc)[2][4])
{
    const int tid = threadIdx.x;
    const int w = tid >> 6, l = tid & 63;
    const int wm = (w >> 1) * 32, wn = (w & 1) * 64;
    const int kc = l >> 4, lr = l & 15;
    const size_t a0 = (size_t)mt * KT * 2048;
    stage_t2(Ath, Atl, Bth, Btl, a0, 0, sAh[0], sAl[0], sBh[0], sBl[0], tid, w);
    for (int t = 0; t < KT; ++t) {
        const int cur = t & 1;
        asm volatile("s_waitcnt vmcnt(0)" ::: "memory");
        __builtin_amdgcn_s_barrier();
        __builtin_amdgcn_sched_barrier(0);
        if (t + 1 < KT)
            stage_t2(Ath, Atl, Bth, Btl, a0 + (size_t)(t + 1) * 2048, (size_t)(t + 1) * 4096,
                     sAh[1 - cur], sAl[1 - cur], sBh[1 - cur], sBl[1 - cur], tid, w);
        bf16x8 ah[2], al[2], bh[4], bl[4];
#pragma unroll
        for (int f = 0; f < 2; f++) {
            int ao = (kc * 64 + wm + f * 16 + lr) * 8;
            ah[f] = *(const bf16x8*)(sAh[cur] + ao);
            al[f] = *(const bf16x8*)(sAl[cur] + ao);
        }
#pragma unroll
        for (int f = 0; f < 4; f++) {
            int bo = (kc * 128 + wn + f * 16 + lr) * 8;
            bh[f] = *(const bf16x8*)(sBh[cur] + bo);
            bl[f] = *(const bf16x8*)(sBl[cur] + bo);
        }
#pragma unroll
        for (int fm = 0; fm < 2; fm++)
#pragma unroll
            for (int fn = 0; fn < 4; fn++) {
                acc[fm][fn] = __builtin_amdgcn_mfma_f32_16x16x32_bf16(ah[fm], bh[fn], acc[fm][fn], 0, 0, 0);
                acc[fm][fn] = __builtin_amdgcn_mfma_f32_16x16x32_bf16(ah[fm], bl[fn], acc[fm][fn], 0, 0, 0);
                acc[fm][fn] = __builtin_amdgcn_mfma_f32_16x16x32_bf16(al[fm], bh[fn], acc[fm][fn], 0, 0, 0);
            }
    }
}

// ============ QKV GEMM bf16x2 tiled -> fp32 out (z selects q/k/v) ============
__global__ __launch_bounds__(256) void qkv_mfma2(const ushort* __restrict__ xh,
    const ushort* __restrict__ xl,
    const ushort* __restrict__ wqh, const ushort* __restrict__ wql,
    const ushort* __restrict__ wkh, const ushort* __restrict__ wkl,
    const ushort* __restrict__ wvh, const ushort* __restrict__ wvl,
    float* __restrict__ qo, float* __restrict__ ko, float* __restrict__ vo)
{
    __shared__ ushort sAh[2][2048], sAl[2][2048], sBh[2][4096], sBl[2][4096];
    const ushort* Bh = blockIdx.z == 0 ? wqh : (blockIdx.z == 1 ? wkh : wvh);
    const ushort* Bl = blockIdx.z == 0 ? wql : (blockIdx.z == 1 ? wkl : wvl);
    float* C = blockIdx.z == 0 ? qo : (blockIdx.z == 1 ? ko : vo);
    int mt = blockIdx.y, ntile = blockIdx.x;
    int m0 = mt * 64, n0 = ntile * 128;
    f32x4 acc[2][4];
#pragma unroll
    for (int i = 0; i < 2; i++)
#pragma unroll
        for (int j = 0; j < 4; j++) acc[i][j] = (f32x4){0.f, 0.f, 0.f, 0.f};
    mfma2_kloop_t(xh, xl, Bh + (size_t)ntile * 32 * 4096, Bl + (size_t)ntile * 32 * 4096,
                  32, mt, sAh, sAl, sBh, sBl, acc);
    const int l = threadIdx.x & 63, w = threadIdx.x >> 6;
    const int wm = (w >> 1) * 32, wn = (w & 1) * 64;
#pragma unroll
    for (int fm = 0; fm < 2; fm++)
#pragma unroll
        for (int fn = 0; fn < 4; fn++)
#pragma unroll
            for (int r = 0; r < 4; r++) {
                int row = m0 + wm + fm * 16 + (l >> 4) * 4 + r;
                int col = n0 + wn + fn * 16 + (l & 15);
                C[(size_t)row * D + col] = acc[fm][fn][r];
            }
}

// ============ WO GEMM bf16x2 tiled + residual -> fp32 ============
__global__ __launch_bounds__(256) void wo_mfma2(const ushort* __restrict__ aht,
    const ushort* __restrict__ alt, const ushort* __restrict__ wh, const ushort* __restrict__ wl,
    const float* __restrict__ resid, float* __restrict__ Cout)
{
    __shared__ ushort sAh[2][2048], sAl[2][2048], sBh[2][4096], sBl[2][4096];
    int mt = blockIdx.y, ntile = blockIdx.x;
    int m0 = mt * 64, n0 = ntile * 128;
    f32x4 acc[2][4];
#pragma unroll
    for (int i = 0; i < 2; i++)
#pragma unroll
        for (int j = 0; j < 4; j++) acc[i][j] = (f32x4){0.f, 0.f, 0.f, 0.f};
    mfma2_kloop_t(aht, alt, wh + (size_t)ntile * 32 * 4096, wl + (size_t)ntile * 32 * 4096,
                  32, mt, sAh, sAl, sBh, sBl, acc);
    const int l = threadIdx.x & 63, w = threadIdx.x >> 6;
    const int wm = (w >> 1) * 32, wn = (w & 1) * 64;
#pragma unroll
    for (int fm = 0; fm < 2; fm++)
#pragma unroll
        for (int fn = 0; fn < 4; fn++)
#pragma unroll
            for (int r = 0; r < 4; r++) {
                int row = m0 + wm + fm * 16 + (l >> 4) * 4 + r;
                int col = n0 + wn + fn * 16 + (l & 15);
                Cout[(size_t)row * D + col] = acc[fm][fn][r] + resid[(size_t)row * D + col];
            }
}

// ============ Flash attention via MFMA (bf16x2 triple-product QK^T and PV) ============
// Grid: (32, 16) = 512 blocks; XCD-aware bijective swizzle; epilogue writes TILED
// hi/lo planes for the WO GEMM's A operand.
__global__ __launch_bounds__(256) void attn_mfma(
    const ushort* __restrict__ qhp, const ushort* __restrict__ qlp,
    const ushort* __restrict__ khp, const ushort* __restrict__ klp,
    const ushort* __restrict__ vth, const ushort* __restrict__ vtl,
    ushort* __restrict__ aht, ushort* __restrict__ alt)
{
    __shared__ ushort sK[2][2][4096];
    __shared__ ushort sV[2][2][4096];
    __shared__ ushort sP[4][2][1024];
    const int n = blockIdx.y * 32 + blockIdx.x;
    const int wg = ((n & 7) << 6) + (n >> 3);   // bijective 512-block XCD swizzle
    const int h = wg >> 5;
    const int qt = 31 - (wg & 31);              // big q-tiles dispatch first (LPT)
    const int tid = threadIdx.x;
    const int w = tid >> 6, l = tid & 63;
    const int g = l >> 4, c = l & 15;
    const size_t hoff = (size_t)h * HD;
    ushort* sPh = &sP[w][0][0];
    ushort* sPl = &sP[w][1][0];

#define STAGE_KV(buf, kt_)                                                        \
  do {                                                                            \
    const int k0s = (kt_) * 64;                                                   \
    int cb0 = w * 64;                                                             \
    int ch0 = cb0 + l;                                                            \
    size_t kg0 = (size_t)(k0s + (ch0 & 63)) * D + hoff + (ch0 >> 6) * 8;          \
    size_t vg0 = (hoff + (ch0 & 63)) * (size_t)S + k0s + (ch0 >> 6) * 8;          \
    async_copy16(khp + kg0, &sK[buf][0][cb0 * 8]);                                \
    async_copy16(klp + kg0, &sK[buf][1][cb0 * 8]);                                \
    async_copy16(vth + vg0, &sV[buf][0][cb0 * 8]);                                \
    async_copy16(vtl + vg0, &sV[buf][1][cb0 * 8]);                                \
    int cb1 = 256 + w * 64;                                                       \
    int ch1 = cb1 + l;                                                            \
    size_t kg1 = (size_t)(k0s + (ch1 & 63)) * D + hoff + (ch1 >> 6) * 8;          \
    size_t vg1 = (hoff + (ch1 & 63)) * (size_t)S + k0s + (ch1 >> 6) * 8;          \
    async_copy16(khp + kg1, &sK[buf][0][cb1 * 8]);                                \
    async_copy16(klp + kg1, &sK[buf][1][cb1 * 8]);                                \
    async_copy16(vth + vg1, &sV[buf][0][cb1 * 8]);                                \
    async_copy16(vtl + vg1, &sV[buf][1][cb1 * 8]);                                \
  } while (0)

    const size_t qrow = (size_t)(qt * 64 + w * 16 + c) * D + hoff;
    bf16x8 aqh0 = *(const bf16x8*)(qhp + qrow + g * 8);
    bf16x8 aqh1 = *(const bf16x8*)(qhp + qrow + 32 + g * 8);
    bf16x8 aql0 = *(const bf16x8*)(qlp + qrow + g * 8);
    bf16x8 aql1 = *(const bf16x8*)(qlp + qrow + 32 + g * 8);

    STAGE_KV(0, 0);
    asm volatile("s_waitcnt vmcnt(0)" ::: "memory");
    __builtin_amdgcn_s_barrier();
    __builtin_amdgcn_sched_barrier(0);

    float m_[4], l_[4];
    f32x4 oacc[4];
#pragma unroll
    for (int r = 0; r < 4; r++) { m_[r] = -3e38f; l_[r] = 0.0f; }
#pragma unroll
    for (int fn = 0; fn < 4; fn++) oacc[fn] = (f32x4){0.f, 0.f, 0.f, 0.f};

    for (int kt = 0; kt <= qt; kt++) {
        const int cur = kt & 1;
        if (kt < qt) STAGE_KV(1 - cur, kt + 1);
        const ushort* sKh = &sK[cur][0][0];
        const ushort* sKl = &sK[cur][1][0];
        bf16x8 b0[4], b1[4], c0[4], c1[4];
#pragma unroll
        for (int fn = 0; fn < 4; fn++) {
            int u0 = (g * 64 + fn * 16 + c) * 8;
            int u1 = ((4 + g) * 64 + fn * 16 + c) * 8;
            b0[fn] = *(const bf16x8*)(sKh + u0);
            b1[fn] = *(const bf16x8*)(sKh + u1);
            c0[fn] = *(const bf16x8*)(sKl + u0);
            c1[fn] = *(const bf16x8*)(sKl + u1);
        }
        f32x4 sacc[4];
#pragma unroll
        for (int fn = 0; fn < 4; fn++) {
            f32x4 a = (f32x4){0.f, 0.f, 0.f, 0.f};
            a = __builtin_amdgcn_mfma_f32_16x16x32_bf16(aqh0, b0[fn], a, 0, 0, 0);
            a = __builtin_amdgcn_mfma_f32_16x16x32_bf16(aqh1, b1[fn], a, 0, 0, 0);
            a = __builtin_amdgcn_mfma_f32_16x16x32_bf16(aqh0, c0[fn], a, 0, 0, 0);
            a = __builtin_amdgcn_mfma_f32_16x16x32_bf16(aqh1, c1[fn], a, 0, 0, 0);
            a = __builtin_amdgcn_mfma_f32_16x16x32_bf16(aql0, b0[fn], a, 0, 0, 0);
            a = __builtin_amdgcn_mfma_f32_16x16x32_bf16(aql1, b1[fn], a, 0, 0, 0);
            sacc[fn] = a;
        }
        if (kt == qt) {
#pragma unroll
            for (int fn = 0; fn < 4; fn++)
#pragma unroll
                for (int r = 0; r < 4; r++)
                    if (fn * 16 + c > w * 16 + g * 4 + r) sacc[fn][r] = -3e38f;
        }
        float alpha[4];
#pragma unroll
        for (int r = 0; r < 4; r++) {
            float rm = fmaxf(fmaxf(sacc[0][r], sacc[1][r]), fmaxf(sacc[2][r], sacc[3][r]));
#pragma unroll
            for (int off = 1; off < 16; off <<= 1) rm = fmaxf(rm, __shfl_xor(rm, off));
            float mn = fmaxf(m_[r], rm);
            alpha[r] = exp2f(m_[r] - mn);
            m_[r] = mn;
            float rs = 0.0f;
#pragma unroll
            for (int fn = 0; fn < 4; fn++) {
                float pp = exp2f(sacc[fn][r] - mn);
                sacc[fn][r] = pp;
                rs += pp;
            }
#pragma unroll
            for (int off = 1; off < 16; off <<= 1) rs += __shfl_xor(rs, off);
            l_[r] = l_[r] * alpha[r] + rs;
        }
#pragma unroll
        for (int fn = 0; fn < 4; fn++)
#pragma unroll
            for (int r = 0; r < 4; r++) oacc[fn][r] *= alpha[r];
#pragma unroll
        for (int fn = 0; fn < 4; fn++) {
            int chunk = fn * 2 + (c >> 3);
#pragma unroll
            for (int r = 0; r < 4; r++) {
                float pp = sacc[fn][r];
                ushort ph = f2bf(pp);
                int off = (chunk * 16 + g * 4 + r) * 8 + (c & 7);
                sPh[off] = ph;
                sPl[off] = f2bf(pp - bf2f(ph));
            }
        }
        const ushort* sVh = &sV[cur][0][0];
        const ushort* sVl = &sV[cur][1][0];
        bf16x8 pa0 = *(const bf16x8*)(sPh + (g * 16 + c) * 8);
        bf16x8 pa1 = *(const bf16x8*)(sPh + ((4 + g) * 16 + c) * 8);
        bf16x8 pb0 = *(const bf16x8*)(sPl + (g * 16 + c) * 8);
        bf16x8 pb1 = *(const bf16x8*)(sPl + ((4 + g) * 16 + c) * 8);
#pragma unroll
        for (int fn = 0; fn < 4; fn++) {
            int u0 = (g * 64 + fn * 16 + c) * 8;
            int u1 = ((4 + g) * 64 + fn * 16 + c) * 8;
            bf16x8 vh0 = *(const bf16x8*)(sVh + u0);
            bf16x8 vh1 = *(const bf16x8*)(sVh + u1);
            bf16x8 vl0 = *(const bf16x8*)(sVl + u0);
            bf16x8 vl1 = *(const bf16x8*)(sVl + u1);
            f32x4 o = oacc[fn];
            o = __builtin_amdgcn_mfma_f32_16x16x32_bf16(pa0, vh0, o, 0, 0, 0);
            o = __builtin_amdgcn_mfma_f32_16x16x32_bf16(pa1, vh1, o, 0, 0, 0);
            o = __builtin_amdgcn_mfma_f32_16x16x32_bf16(pa0, vl0, o, 0, 0, 0);
            o = __builtin_amdgcn_mfma_f32_16x16x32_bf16(pa1, vl1, o, 0, 0, 0);
            o = __builtin_amdgcn_mfma_f32_16x16x32_bf16(pb0, vh0, o, 0, 0, 0);
            o = __builtin_amdgcn_mfma_f32_16x16x32_bf16(pb1, vh1, o, 0, 0, 0);
            oacc[fn] = o;
        }
        if (kt < qt) {
            asm volatile("s_waitcnt vmcnt(0)" ::: "memory");
            __builtin_amdgcn_s_barrier();
            __builtin_amdgcn_sched_barrier(0);
        }
    }
    // ---- epilogue: normalize + store TILED bf16x2 planes (WO's A operand) ----
#pragma unroll
    for (int r = 0; r < 4; r++) {
        float inv = 1.0f / l_[r];
        int rowin = w * 16 + g * 4 + r;
#pragma unroll
        for (int fn = 0; fn < 4; fn++) {
            float v = oacc[fn][r] * inv;
            ushort hi = f2bf(v);
            size_t ta = (((size_t)qt * 32 + h * 2 + (fn >> 1)) * 256
                         + (size_t)((fn * 2 + (c >> 3)) & 3) * 64 + rowin) * 8 + (c & 7);
            aht[ta] = hi;
            alt[ta] = f2bf(v - bf2f(hi));
        }
    }
#undef STAGE_KV
}

// ============ Router (fp32 — routing must match reference exactly) ============
__global__ __launch_bounds__(64) void router_kernel(const float* __restrict__ x,
    const float* __restrict__ wr, int* __restrict__ ei, float* __restrict__ ew,
    int* __restrict__ counts, float* __restrict__ prob_sums, float* __restrict__ z_sum)
{
    int t = blockIdx.x, lane = threadIdx.x;
    const float* xr = x + (size_t)t * D;
    float p[E] = {};
    for (int d = lane; d < D; d += 64) {
        float xd = xr[d];
        const float* wrow = wr + d * E;
#pragma unroll
        for (int e = 0; e < E; e++) p[e] = fmaf(xd, wrow[e], p[e]);
    }
#pragma unroll
    for (int off = 32; off > 0; off >>= 1) {
#pragma unroll
        for (int e = 0; e < E; e++) p[e] += __shfl_xor(p[e], off);
    }
    float m = p[0];
#pragma unroll
    for (int e = 1; e < E; e++) m = fmaxf(m, p[e]);
    float sum = 0.0f, pr[E];
#pragma unroll
    for (int e = 0; e < E; e++) { pr[e] = expf(p[e] - m); sum += pr[e]; }
    float invs = 1.0f / sum;
#pragma unroll
    for (int e = 0; e < E; e++) pr[e] *= invs;
    float lse = m + logf(sum);
    int e1 = 0; float b1 = pr[0];
#pragma unroll
    for (int e = 1; e < E; e++) if (pr[e] > b1) { b1 = pr[e]; e1 = e; }
    int e2 = -1; float b2 = -1.0f;
#pragma unroll
    for (int e = 0; e < E; e++) if (e != e1 && pr[e] > b2) { b2 = pr[e]; e2 = e; }
    float wsum = b1 + b2;
    if (lane == 0) {
        ei[2 * t] = e1; ei[2 * t + 1] = e2;
        ew[2 * t] = b1 / wsum; ew[2 * t + 1] = b2 / wsum;
        atomicAdd(&counts[e1], 1);
        atomicAdd(&counts[e2], 1);
        atomicAdd(z_sum, lse * lse);
    }
    if (lane < E) atomicAdd(&prob_sums[lane], pr[lane]);
}

__global__ void zero_kernel(int* counts, float* prob_sums, float* z_sum)
{
    int tid = threadIdx.x;
    if (tid < E) { counts[tid] = 0; prob_sums[tid] = 0.0f; }
    if (tid == 0) *z_sum = 0.0f;
}

__global__ void finalize_kernel(const int* __restrict__ counts, const float* __restrict__ prob_sums,
    const float* __restrict__ z_sum, int* __restrict__ offs, int* __restrict__ cursor,
    float* __restrict__ aux_out)
{
    if (threadIdx.x == 0) {
        int off = 0;
        for (int e = 0; e < E; e++) { offs[e] = off; cursor[e] = off; off += counts[e]; }
        float z = 1e-3f * (*z_sum) * (1.0f / S);
        float lb = 0.0f;
        for (int e = 0; e < E; e++) lb += ((float)counts[e] / (float)S) * (prob_sums[e] / (float)S);
        lb *= 1e-2f;
        *aux_out = z + lb;
    }
}

__global__ __launch_bounds__(256) void scatter_kernel(const int* __restrict__ ei,
    int* __restrict__ cursor, int* __restrict__ tlist, int* __restrict__ slot_of)
{
    int t = blockIdx.x * 256 + threadIdx.x;
    if (t >= S) return;
#pragma unroll
    for (int kk = 0; kk < 2; kk++) {
        int e = ei[2 * t + kk];
        int slot = atomicAdd(&cursor[e], 1);
        tlist[slot] = t;
        slot_of[2 * t + kk] = slot;
    }
}

// ============ Gather -> TILED xgT: per 64-slot tile, 32 k-tiles of 256 chunks ============
__global__ __launch_bounds__(128) void gather_kernel(const ushort* __restrict__ xbf,
    const int* __restrict__ tlist, ushort* __restrict__ xgT)
{
    int slot = blockIdx.x;
    int tid = threadIdx.x;   // chunk of 8 bf16: d0 = tid*8
    bf16x8 v;
    if (slot < NSLOTS) {
        int tok = tlist[slot];
        v = *(const bf16x8*)(xbf + (size_t)tok * D + tid * 8);
    } else {
        v = (bf16x8){0, 0, 0, 0, 0, 0, 0, 0};
    }
    size_t addr = (((size_t)(slot >> 6) * 32 + (tid >> 2)) * 256
                   + (size_t)(tid & 3) * 64 + (slot & 63)) * 8;
    *(bf16x8*)(xgT + addr) = v;
}

// ============ MoE gate+up GEMM, N-concat, 64x128 tile, BK=32, depth-2, TILED operands ============
__global__ __launch_bounds__(256) void moe_gateup_mfma(const ushort* __restrict__ xgT,
    const ushort* __restrict__ wgT, const ushort* __restrict__ wuT,
    ushort* __restrict__ Hg, ushort* __restrict__ Hu,
    const int* __restrict__ offs, const int* __restrict__ cnts)
{
    const int e = blockIdx.z;
    const int cnt = cnts[e];
    const int m0 = blockIdx.y * 64;
    if (m0 >= cnt) return;
    const int off = offs[e];
    const int n0g = blockIdx.x * 128;
    const bool isg = n0g < F;
    const int p = isg ? (n0g >> 7) : ((n0g - F) >> 7);
    const ushort* Wt = (isg ? wgT : wuT) + (size_t)e * F * D + (size_t)p * 32 * 4096;
    ushort* Outp = isg ? Hg : Hu;
    const int ncol0 = isg ? n0g : n0g - F;
    __shared__ ushort As[3][2048], Ws[3][4096];
    const int tid = threadIdx.x;
    const int w = tid >> 6, l = tid & 63;
    const int wm = (w >> 1) * 32, wn = (w & 1) * 64;
    const int kc = l >> 4, lr = l & 15;
    const int wo8 = w * 512;
    // per-lane slot addressing (expert offset may be tile-misaligned)
    const int sl = off + m0 + l;
    const size_t A0 = (size_t)(sl >> 6) * 65536 + ((size_t)w * 64 + (sl & 63)) * 8;

#define STAGE_GU(buf, t_) do {                                                    \
    async_copy16(xgT + A0 + (size_t)(t_) * 2048, As[buf] + wo8);                  \
    async_copy16(Wt + (size_t)(t_) * 4096 + (size_t)tid * 8, Ws[buf] + wo8);      \
    async_copy16(Wt + (size_t)(t_) * 4096 + (size_t)(256 + tid) * 8, Ws[buf] + 2048 + wo8); \
} while (0)

    f32x4 acc[2][4];
#pragma unroll
    for (int i = 0; i < 2; i++)
#pragma unroll
        for (int j = 0; j < 4; j++) acc[i][j] = (f32x4){0.f, 0.f, 0.f, 0.f};

    const int NT = D / 32;   // 32
    STAGE_GU(0, 0);
    STAGE_GU(1, 1);
    for (int t = 0; t < NT; ++t) {
        const int cur = t % 3;
        if (t + 1 < NT) { asm volatile("s_waitcnt vmcnt(3)" ::: "memory"); }
        else            { asm volatile("s_waitcnt vmcnt(0)" ::: "memory"); }
        __builtin_amdgcn_s_barrier();
        __builtin_amdgcn_sched_barrier(0);
        if (t + 2 < NT) STAGE_GU((t + 2) % 3, t + 2);
        bf16x8 af[2], wf[4];
#pragma unroll
        for (int f = 0; f < 2; f++)
            af[f] = *(const bf16x8*)(As[cur] + (kc * 64 + wm + f * 16 + lr) * 8);
#pragma unroll
        for (int f = 0; f < 4; f++)
            wf[f] = *(const bf16x8*)(Ws[cur] + (kc * 128 + wn + f * 16 + lr) * 8);
#pragma unroll
        for (int fm = 0; fm < 2; fm++)
#pragma unroll
            for (int fn = 0; fn < 4; fn++)
                acc[fm][fn] = __builtin_amdgcn_mfma_f32_16x16x32_bf16(af[fm], wf[fn], acc[fm][fn], 0, 0, 0);
    }
#undef STAGE_GU
#pragma unroll
    for (int fm = 0; fm < 2; fm++)
#pragma unroll
        for (int fn = 0; fn < 4; fn++)
#pragma unroll
            for (int r = 0; r < 4; r++) {
                int rloc = m0 + wm + fm * 16 + (l >> 4) * 4 + r;
                if (rloc < cnt) {
                    int col = ncol0 + wn + fn * 16 + (l & 15);
                    Outp[(size_t)(off + rloc) * F + col] = f2bf(acc[fm][fn][r]);
                }
            }
}

// ============ SiLU(g)*u elementwise -> TILED HbT (down's A operand) ============
__global__ __launch_bounds__(256) void silu_kernel(const ushort* __restrict__ Gout,
    const ushort* __restrict__ Uout, ushort* __restrict__ HbT)
{
    int slot = blockIdx.x;
    int tid = threadIdx.x;
    int f0 = tid * 8;
    bf16x8 gv = *(const bf16x8*)(Gout + (size_t)slot * F + f0);
    bf16x8 uv = *(const bf16x8*)(Uout + (size_t)slot * F + f0);
    bf16x8 o;
#pragma unroll
    for (int j = 0; j < 8; j++) {
        float g = bf2f((ushort)gv[j]);
        float u = bf2f((ushort)uv[j]);
        o[j] = (short)f2bf(g / (1.0f + expf(-g)) * u);
    }
    size_t addr = (((size_t)(slot >> 6) * 64 + (tid >> 2)) * 256
                   + (size_t)(tid & 3) * 64 + (slot & 63)) * 8;
    *(bf16x8*)(HbT + addr) = o;
}

// ============ MoE down GEMM (64x128 tile, BK=32, depth-2, TILED operands) ============
__global__ __launch_bounds__(256) void moe_down_mfma(const ushort* __restrict__ HbT,
    const ushort* __restrict__ wdT, ushort* __restrict__ yb,
    const int* __restrict__ offs, const int* __restrict__ cnts)
{
    const int e = blockIdx.z;
    const int cnt = cnts[e];
    const int m0 = blockIdx.y * 64;
    if (m0 >= cnt) return;
    const int off = offs[e];
    const int p = blockIdx.x;            // n panel over D (8 panels)
    const int n0 = p * 128;
    const ushort* Wt = wdT + (size_t)e * D * F + (size_t)p * 64 * 4096;
    __shared__ ushort As[3][2048], Bs[3][4096];
    const int tid = threadIdx.x;
    const int w = tid >> 6, l = tid & 63;
    const int wm = (w >> 1) * 32, wn = (w & 1) * 64;
    const int kc = l >> 4, lr = l & 15;
    const int wo8 = w * 512;
    const int sl = off + m0 + l;
    const size_t A0 = (size_t)(sl >> 6) * 131072 + ((size_t)w * 64 + (sl & 63)) * 8;

#define STAGE_DN(buf, t_) do {                                                    \
    async_copy16(HbT + A0 + (size_t)(t_) * 2048, As[buf] + wo8);                  \
    async_copy16(Wt + (size_t)(t_) * 4096 + (size_t)tid * 8, Bs[buf] + wo8);      \
    async_copy16(Wt + (size_t)(t_) * 4096 + (size_t)(256 + tid) * 8, Bs[buf] + 2048 + wo8); \
} while (0)

    f32x4 acc[2][4];
#pragma unroll
    for (int i = 0; i < 2; i++)
#pragma unroll
        for (int j = 0; j < 4; j++) acc[i][j] = (f32x4){0.f,0.f,0.f,0.f};

    const int NT = F / 32;   // 64
    STAGE_DN(0, 0);
    STAGE_DN(1, 1);
    for (int t = 0; t < NT; ++t) {
        const int cur = t % 3;
        if (t + 1 < NT) { asm volatile("s_waitcnt vmcnt(3)" ::: "memory"); }
        else            { asm volatile("s_waitcnt vmcnt(0)" ::: "memory"); }
        __builtin_amdgcn_s_barrier();
        __builtin_amdgcn_sched_barrier(0);
        if (t + 2 < NT) STAGE_DN((t + 2) % 3, t + 2);
        bf16x8 af[2], bfr[4];
#pragma unroll
        for (int f = 0; f < 2; f++)
            af[f] = *(const bf16x8*)(As[cur] + (kc * 64 + wm + f * 16 + lr) * 8);
#pragma unroll
        for (int f = 0; f < 4; f++)
            bfr[f] = *(const bf16x8*)(Bs[cur] + (kc * 128 + wn + f * 16 + lr) * 8);
#pragma unroll
        for (int fm = 0; fm < 2; fm++)
#pragma unroll
            for (int fn = 0; fn < 4; fn++)
                acc[fm][fn] = __builtin_amdgcn_mfma_f32_16x16x32_bf16(af[fm], bfr[fn], acc[fm][fn], 0, 0, 0);
    }
#undef STAGE_DN
#pragma unroll
    for (int fm = 0; fm < 2; fm++)
#pragma unroll
        for (int fn = 0; fn < 4; fn++)
#pragma unroll
            for (int r = 0; r < 4; r++) {
                int rloc = m0 + wm + fm * 16 + (l >> 4) * 4 + r;
                if (rloc < cnt) {
                    int col = n0 + wn + fn * 16 + (l & 15);
                    yb[(size_t)(off + rloc) * D + col] = f2bf(acc[fm][fn][r]);
                }
            }
}

// ============ Combine ============
__global__ __launch_bounds__(256) void combine_kernel(const float* __restrict__ hs2,
    const ushort* __restrict__ yb, const float* __restrict__ ew,
    const int* __restrict__ slot_of, float* __restrict__ out)
{
    int t = blockIdx.x, tid = threadIdx.x;
    int s0 = slot_of[2 * t], s1 = slot_of[2 * t + 1];
    float w0 = ew[2 * t], w1 = ew[2 * t + 1];
    float4 a = *(const float4*)(hs2 + (size_t)t * D + tid * 4);
    ushort4 y0 = *(const ushort4*)(yb + (size_t)s0 * D + tid * 4);
    ushort4 y1 = *(const ushort4*)(yb + (size_t)s1 * D + tid * 4);
    float4 o;
    o.x = a.x + w0 * bf2f(y0.x) + w1 * bf2f(y1.x);
    o.y = a.y + w0 * bf2f(y0.y) + w1 * bf2f(y1.y);
    o.z = a.z + w0 * bf2f(y0.z) + w1 * bf2f(y1.z);
    o.w = a.w + w0 * bf2f(y0.w) + w1 * bf2f(y1.w);
    *(float4*)(out + (size_t)t * D + tid * 4) = o;
}

// ============ launch ============
extern "C" void kernel_launch(void* const* d_in, const int* in_sizes, int n_in,
                              void* d_out, int out_size, void* d_ws, size_t ws_size,
                              hipStream_t stream)
{
    (void)in_sizes; (void)n_in; (void)out_size; (void)ws_size;
    const float* hs   = (const float*)d_in[0];
    const float* ln1w = (const float*)d_in[3];
    const float* ln1b = (const float*)d_in[4];
    const float* ln2w = (const float*)d_in[5];
    const float* ln2b = (const float*)d_in[6];
    const float* wq   = (const float*)d_in[7];
    const float* wk   = (const float*)d_in[8];
    const float* wv   = (const float*)d_in[9];
    const float* wo   = (const float*)d_in[10];
    const float* wr   = (const float*)d_in[11];
    const float* wg   = (const float*)d_in[12];
    const float* wu   = (const float*)d_in[13];
    const float* wd   = (const float*)d_in[14];
    float* out = (float*)d_out;

    const size_t TD = (size_t)S * D;
    char* p = (char*)d_ws;
    auto alloc = [&](size_t bytes) { char* r = p; p += (bytes + 255) & ~(size_t)255; return r; };

    ushort* wgt  = (ushort*)alloc((size_t)E * D * F * 2);   // tiled
    ushort* wut  = (ushort*)alloc((size_t)E * D * F * 2);   // tiled
    ushort* wdt  = (ushort*)alloc((size_t)E * D * F * 2);   // tiled
    ushort* wqh  = (ushort*)alloc((size_t)D * D * 2);       // tiled hi/lo planes
    ushort* wqlo = (ushort*)alloc((size_t)D * D * 2);
    ushort* wkh  = (ushort*)alloc((size_t)D * D * 2);
    ushort* wklo = (ushort*)alloc((size_t)D * D * 2);
    ushort* wvh  = (ushort*)alloc((size_t)D * D * 2);
    ushort* wvlo = (ushort*)alloc((size_t)D * D * 2);
    ushort* woh  = (ushort*)alloc((size_t)D * D * 2);
    ushort* wolo = (ushort*)alloc((size_t)D * D * 2);
    ushort* xh   = (ushort*)alloc(TD * 2);   // ln1 tiled hi; later rope Q hi (row)
    ushort* xl   = (ushort*)alloc(TD * 2);   // ln1 tiled lo; later rope Q lo (row)
    float*  qb   = (float*)alloc(TD * 4);    // fp32 Q; later Gout (bf16, aliased)
    float*  kb   = (float*)alloc(TD * 4);
    float*  vb   = (float*)alloc(TD * 4);    // fp32 V; later Uout (bf16, aliased)
    ushort* ath  = (ushort*)alloc(TD * 2);   // attn out TILED hi
    ushort* atl  = (ushort*)alloc(TD * 2);   // attn out TILED lo
    float*  hs2  = (float*)alloc(TD * 4);
    float*  xf32 = (float*)alloc(TD * 4);
    ushort* xbf  = (ushort*)alloc(TD * 2);
    ushort* xg   = (ushort*)alloc((size_t)NPAD * D * 2);    // tiled
    ushort* Hb   = (ushort*)alloc((size_t)NPAD * F * 2);    // tiled
    ushort* yb   = (ushort*)alloc((size_t)NPAD * D * 2);    // row-major
    ushort* khp  = (ushort*)alloc(TD * 2);   // K bf16 hi (post-rope), row-major [S][D]
    ushort* klp  = (ushort*)alloc(TD * 2);
    ushort* vth  = (ushort*)alloc(TD * 2);   // V^T bf16 hi, [D][S]
    ushort* vtl  = (ushort*)alloc(TD * 2);
    float*  ewb       = (float*)alloc(2 * S * 4);
    float*  prob_sums = (float*)alloc(8 * 4);
    float*  z_sum     = (float*)alloc(8 * 4);
    int* ei      = (int*)alloc(2 * S * 4);
    int* slot_of = (int*)alloc(2 * S * 4);
    int* tlist   = (int*)alloc(NSLOTS * 4);
    int* counts  = (int*)alloc(8 * 4);
    int* offs    = (int*)alloc(8 * 4);
    int* cursor  = (int*)alloc(8 * 4);

    ushort* Gout = (ushort*)qb;   // row-major [NSLOTS][F] over qb+kb
    ushort* Uout = (ushort*)vb;   // row-major over vb+ath'... vb(8.39)+ath(4.19)+atl(4.19)=16.78MB

    // ---- weight prep (tiled layouts) ----
    castTile2W_kernel<<<dim3(D / 128, D / 32), 256, 0, stream>>>(wq, wqh, wqlo, D, D);
    castTile2W_kernel<<<dim3(D / 128, D / 32), 256, 0, stream>>>(wk, wkh, wklo, D, D);
    castTile2W_kernel<<<dim3(D / 128, D / 32), 256, 0, stream>>>(wv, wvh, wvlo, D, D);
    castTile2W_kernel<<<dim3(D / 128, D / 32), 256, 0, stream>>>(wo, woh, wolo, D, D);
    castTileW_kernel<<<dim3(F / 128, D / 32, E), 256, 0, stream>>>(wg, wgt, D, F);
    castTileW_kernel<<<dim3(F / 128, D / 32, E), 256, 0, stream>>>(wu, wut, D, F);
    castTileW_kernel<<<dim3(D / 128, F / 32, E), 256, 0, stream>>>(wd, wdt, F, D);

    // ---- attention sub-block ----
    ln_kernel<<<S, 256, 0, stream>>>(hs, ln1w, ln1b, nullptr, nullptr, xh, xl);
    qkv_mfma2<<<dim3(D / 128, S / 64, 3), 256, 0, stream>>>(xh, xl, wqh, wqlo, wkh, wklo, wvh, wvlo, qb, kb, vb);
    rope_cast<<<S, 512, 0, stream>>>(qb, kb, xh, xl, khp, klp);
    castT2_kernel<<<dim3(D / 64, S / 64), 256, 0, stream>>>(vb, vth, vtl, S, D);
    attn_mfma<<<dim3(32, 16), 256, 0, stream>>>(xh, xl, khp, klp, vth, vtl, ath, atl);
    wo_mfma2<<<dim3(D / 128, S / 64), 256, 0, stream>>>(ath, atl, woh, wolo, hs, hs2);

    // ---- MoE sub-block ----
    ln_kernel<<<S, 256, 0, stream>>>(hs2, ln2w, ln2b, xf32, xbf, nullptr, nullptr);
    zero_kernel<<<1, 64, 0, stream>>>(counts, prob_sums, z_sum);
    router_kernel<<<S, 64, 0, stream>>>(xf32, wr, ei, ewb, counts, prob_sums, z_sum);
    finalize_kernel<<<1, 64, 0, stream>>>(counts, prob_sums, z_sum, offs, cursor, out + TD);
    scatter_kernel<<<S / 256, 256, 0, stream>>>(ei, cursor, tlist, slot_of);
    gather_kernel<<<NPAD, 128, 0, stream>>>(xbf, tlist, xg);
    moe_gateup_mfma<<<dim3(2 * F / 128, NSLOTS / 64, E), 256, 0, stream>>>(xg, wgt, wut, Gout, Uout, offs, counts);
    silu_kernel<<<NSLOTS, 256, 0, stream>>>(Gout, Uout, Hb);
    moe_down_mfma<<<dim3(D / 128, NSLOTS / 64, E), 256, 0, stream>>>(Hb, wdt, yb, offs, counts);
    combine_kernel<<<S, 256, 0, stream>>>(hs2, yb, ewb, slot_of, out);
}